// Round 1
// baseline (2407.676 us; speedup 1.0000x reference)
//
#include <hip/hip_runtime.h>
#include <math.h>

#define N_NODES 100000
#define N_EDGES 1200000
#define N_GRAPHS 512
#define HID 64
#define HEADS 4
#define HEAD_DIM 16
#define IN_DIM 24
#define GDIM 10

// ---------- helpers ----------

__device__ __forceinline__ float wave_sum64(float v) {
#pragma unroll
  for (int m = 32; m >= 1; m >>= 1) v += __shfl_xor(v, m, 64);
  return v;
}

// reduce within aligned groups of 16 lanes (one attention head)
__device__ __forceinline__ float head_sum16(float v) {
#pragma unroll
  for (int m = 8; m >= 1; m >>= 1) v += __shfl_xor(v, m, 64);
  return v;
}

// order-preserving float -> uint map (for atomicMax on floats)
__device__ __forceinline__ unsigned enc_f(float f) {
  unsigned u = __float_as_uint(f);
  return (u & 0x80000000u) ? ~u : (u | 0x80000000u);
}
__device__ __forceinline__ float dec_f(unsigned u) {
  unsigned v = (u & 0x80000000u) ? (u & 0x7FFFFFFFu) : ~u;
  return __uint_as_float(v);
}

__device__ __forceinline__ float lrelu02(float x) {
  return x > 0.f ? x : 0.2f * x;
}

// ---------- kernels ----------

__global__ void k_zero(float* __restrict__ p, int n) {
  int i = blockIdx.x * blockDim.x + threadIdx.x;
  if (i < n) p[i] = 0.f;
}

__global__ void k_pool_init(float* __restrict__ add_p, float* __restrict__ sum_p,
                            unsigned* __restrict__ max_enc, float* __restrict__ cnt) {
  int i = blockIdx.x * blockDim.x + threadIdx.x;
  if (i < N_GRAPHS * HID) {
    add_p[i] = 0.f;
    sum_p[i] = 0.f;
    max_enc[i] = enc_f(-INFINITY);
  }
  if (i < N_GRAPHS) cnt[i] = 0.f;
}

// input projection + LN + relu. one wave per node, lane = feature.
__global__ void k_input(const float* __restrict__ x, const float* __restrict__ gf,
                        const int* __restrict__ batch,
                        const float* __restrict__ w, const float* __restrict__ b,
                        const float* __restrict__ lng, const float* __restrict__ lnb,
                        float* __restrict__ h) {
  int n = (blockIdx.x * blockDim.x + threadIdx.x) >> 6;
  int lane = threadIdx.x & 63;
  if (n >= N_NODES) return;
  int g = batch[n];
  float feat = 0.f;
  if (lane < IN_DIM) feat = x[n * IN_DIM + lane];
  else if (lane < IN_DIM + GDIM) feat = gf[g * GDIM + (lane - IN_DIM)];
  float acc = b[lane];
#pragma unroll
  for (int k = 0; k < IN_DIM + GDIM; ++k) {
    float fk = __shfl(feat, k, 64);
    acc += fk * w[k * HID + lane];
  }
  float mean = wave_sum64(acc) * (1.f / 64.f);
  float d = acc - mean;
  float var = wave_sum64(d * d) * (1.f / 64.f);
  float v = d * rsqrtf(var + 1e-5f) * lng[lane] + lnb[lane];
  h[n * HID + lane] = fmaxf(v, 0.f);
}

// GIN neighbor sum: one wave per edge, atomic add of 64-float row.
__global__ void k_gin_agg(const int* __restrict__ src, const int* __restrict__ dst,
                          const float* __restrict__ h, float* __restrict__ agg) {
  int e = (blockIdx.x * blockDim.x + threadIdx.x) >> 6;
  int lane = threadIdx.x & 63;
  if (e >= N_EDGES) return;
  int s = src[e], d = dst[e];
  atomicAdd(&agg[(size_t)d * HID + lane], h[(size_t)s * HID + lane]);
}

// GIN node update: z=(1+eps)h+agg -> w1(64x128)+b1 -> BN -> relu -> w2(128x64)+b2 -> LN -> relu -> +ident
__global__ void k_gin_node(const float* __restrict__ agg, const float* __restrict__ eps_p,
                           const float* __restrict__ w1, const float* __restrict__ b1,
                           const float* __restrict__ bng, const float* __restrict__ bnb,
                           const float* __restrict__ bnm, const float* __restrict__ bnv,
                           const float* __restrict__ w2, const float* __restrict__ b2,
                           const float* __restrict__ lng, const float* __restrict__ lnb,
                           float* __restrict__ h) {
  int n = (blockIdx.x * blockDim.x + threadIdx.x) >> 6;
  int lane = threadIdx.x & 63;
  if (n >= N_NODES) return;
  float hj = h[(size_t)n * HID + lane];
  float z = (1.f + eps_p[0]) * hj + agg[(size_t)n * HID + lane];
  float a0 = b1[lane], a1 = b1[lane + 64];
  for (int k = 0; k < 64; ++k) {
    float zk = __shfl(z, k, 64);
    a0 += zk * w1[k * 128 + lane];
    a1 += zk * w1[k * 128 + 64 + lane];
  }
  a0 = (a0 - bnm[lane]) * rsqrtf(bnv[lane] + 1e-5f) * bng[lane] + bnb[lane];
  a1 = (a1 - bnm[lane + 64]) * rsqrtf(bnv[lane + 64] + 1e-5f) * bng[lane + 64] + bnb[lane + 64];
  a0 = fmaxf(a0, 0.f);
  a1 = fmaxf(a1, 0.f);
  float o = b2[lane];
  for (int k = 0; k < 64; ++k) {
    float r0 = __shfl(a0, k, 64);
    float r1 = __shfl(a1, k, 64);
    o += r0 * w2[k * 64 + lane] + r1 * w2[(64 + k) * 64 + lane];
  }
  float mean = wave_sum64(o) * (1.f / 64.f);
  float d = o - mean;
  float var = wave_sum64(d * d) * (1.f / 64.f);
  float v = d * rsqrtf(var + 1e-5f) * lng[lane] + lnb[lane];
  h[(size_t)n * HID + lane] = fmaxf(v, 0.f) + hj;
}

// GAT per-node precompute: xp = h @ W, per-head asr/adt dots, init m with self-loop e
__global__ void k_gat_pre(const float* __restrict__ h, const float* __restrict__ w,
                          const float* __restrict__ asrc, const float* __restrict__ adst,
                          float* __restrict__ xp, float* __restrict__ asr,
                          float* __restrict__ adt, unsigned* __restrict__ menc) {
  int n = (blockIdx.x * blockDim.x + threadIdx.x) >> 6;
  int lane = threadIdx.x & 63;
  if (n >= N_NODES) return;
  float hj = h[(size_t)n * HID + lane];
  float p = 0.f;
  for (int k = 0; k < 64; ++k) {
    float hk = __shfl(hj, k, 64);
    p += hk * w[k * 64 + lane];
  }
  xp[(size_t)n * HID + lane] = p;
  int head = lane >> 4;
  float as = head_sum16(p * asrc[head * HEAD_DIM + (lane & 15)]);
  float ad = head_sum16(p * adst[head * HEAD_DIM + (lane & 15)]);
  if ((lane & 15) == 0) {
    asr[n * HEADS + head] = as;
    adt[n * HEADS + head] = ad;
    menc[n * HEADS + head] = enc_f(lrelu02(as + ad));  // self-loop seeds the max
  }
}

// edge pass 1: segment max of e over dst. one thread per (edge, head)
__global__ void k_gat_emax(const int* __restrict__ src, const int* __restrict__ dst,
                           const float* __restrict__ asr, const float* __restrict__ adt,
                           unsigned* __restrict__ menc) {
  int t = blockIdx.x * blockDim.x + threadIdx.x;
  if (t >= N_EDGES * HEADS) return;
  int e = t >> 2, hd = t & 3;
  int s = src[e], d = dst[e];
  float ev = lrelu02(asr[s * HEADS + hd] + adt[d * HEADS + hd]);
  atomicMax(&menc[d * HEADS + hd], enc_f(ev));
}

// node pass: ssum initialized with self-loop contribution
__global__ void k_gat_sinit(const float* __restrict__ asr, const float* __restrict__ adt,
                            const unsigned* __restrict__ menc, float* __restrict__ ssum) {
  int t = blockIdx.x * blockDim.x + threadIdx.x;
  if (t >= N_NODES * HEADS) return;
  float el = lrelu02(asr[t] + adt[t]);
  ssum[t] = expf(el - dec_f(menc[t]));
}

// edge pass 2: segment sum of exp(e - m)
__global__ void k_gat_esum(const int* __restrict__ src, const int* __restrict__ dst,
                           const float* __restrict__ asr, const float* __restrict__ adt,
                           const unsigned* __restrict__ menc, float* __restrict__ ssum) {
  int t = blockIdx.x * blockDim.x + threadIdx.x;
  if (t >= N_EDGES * HEADS) return;
  int e = t >> 2, hd = t & 3;
  int s = src[e], d = dst[e];
  float ev = lrelu02(asr[s * HEADS + hd] + adt[d * HEADS + hd]);
  float p = expf(ev - dec_f(menc[d * HEADS + hd]));
  atomicAdd(&ssum[d * HEADS + hd], p);
}

// node pass: out initialized with self-loop alpha * xp
__global__ void k_gat_oinit(const float* __restrict__ xp, const float* __restrict__ asr,
                            const float* __restrict__ adt, const unsigned* __restrict__ menc,
                            const float* __restrict__ ssum, float* __restrict__ out) {
  int n = (blockIdx.x * blockDim.x + threadIdx.x) >> 6;
  int lane = threadIdx.x & 63;
  if (n >= N_NODES) return;
  int head = lane >> 4;
  float el = lrelu02(asr[n * HEADS + head] + adt[n * HEADS + head]);
  float alpha = expf(el - dec_f(menc[n * HEADS + head])) / ssum[n * HEADS + head];
  out[(size_t)n * HID + lane] = alpha * xp[(size_t)n * HID + lane];
}

// edge pass 3: out[dst] += alpha * xp[src]. one wave per edge.
__global__ void k_gat_eagg(const int* __restrict__ src, const int* __restrict__ dst,
                           const float* __restrict__ xp, const float* __restrict__ asr,
                           const float* __restrict__ adt, const unsigned* __restrict__ menc,
                           const float* __restrict__ ssum, float* __restrict__ out) {
  int e = (blockIdx.x * blockDim.x + threadIdx.x) >> 6;
  int lane = threadIdx.x & 63;
  if (e >= N_EDGES) return;
  int s = src[e], d = dst[e];
  int head = lane >> 4;
  float ev = lrelu02(asr[s * HEADS + head] + adt[d * HEADS + head]);
  float alpha = expf(ev - dec_f(menc[d * HEADS + head])) / ssum[d * HEADS + head];
  atomicAdd(&out[(size_t)d * HID + lane], alpha * xp[(size_t)s * HID + lane]);
}

// GAT finish: +bias, LN, elu, residual
__global__ void k_gat_fin(const float* __restrict__ out, const float* __restrict__ bias,
                          const float* __restrict__ lng, const float* __restrict__ lnb,
                          float* __restrict__ h) {
  int n = (blockIdx.x * blockDim.x + threadIdx.x) >> 6;
  int lane = threadIdx.x & 63;
  if (n >= N_NODES) return;
  float o = out[(size_t)n * HID + lane] + bias[lane];
  float mean = wave_sum64(o) * (1.f / 64.f);
  float d = o - mean;
  float var = wave_sum64(d * d) * (1.f / 64.f);
  float v = d * rsqrtf(var + 1e-5f) * lng[lane] + lnb[lane];
  float e = v > 0.f ? v : expm1f(v);
  h[(size_t)n * HID + lane] = e + h[(size_t)n * HID + lane];
}

// pooling: add pool of gin_out
__global__ void k_pool_add(const float* __restrict__ h, const int* __restrict__ batch,
                           float* __restrict__ add_p, float* __restrict__ cnt) {
  int n = (blockIdx.x * blockDim.x + threadIdx.x) >> 6;
  int lane = threadIdx.x & 63;
  if (n >= N_NODES) return;
  int g = batch[n];
  atomicAdd(&add_p[g * HID + lane], h[(size_t)n * HID + lane]);
  if (lane == 0) atomicAdd(&cnt[g], 1.f);
}

// pooling: sum (for mean) + max of gat_out
__global__ void k_pool_meanmax(const float* __restrict__ h, const int* __restrict__ batch,
                               float* __restrict__ sum_p, unsigned* __restrict__ max_enc) {
  int n = (blockIdx.x * blockDim.x + threadIdx.x) >> 6;
  int lane = threadIdx.x & 63;
  if (n >= N_NODES) return;
  int g = batch[n];
  float v = h[(size_t)n * HID + lane];
  atomicAdd(&sum_p[g * HID + lane], v);
  atomicMax(&max_enc[g * HID + lane], enc_f(v));
}

// final per-graph MLP. one 64-thread block (one wave) per graph.
__global__ void k_final(const float* __restrict__ add_p, const float* __restrict__ sum_p,
                        const unsigned* __restrict__ max_enc, const float* __restrict__ cnt,
                        const float* __restrict__ fw1, const float* __restrict__ fb1,
                        const float* __restrict__ flng, const float* __restrict__ flnb,
                        const float* __restrict__ fw2, const float* __restrict__ fb2,
                        const float* __restrict__ pw1, const float* __restrict__ pb1,
                        const float* __restrict__ pw2, const float* __restrict__ pb2,
                        float* __restrict__ out) {
  __shared__ float buf[192];
  __shared__ float r1s[64];
  __shared__ float r2s[32];
  __shared__ float r3s[16];
  int g = blockIdx.x;
  int lane = threadIdx.x;
  float c = fmaxf(cnt[g], 1.f);
  buf[lane] = add_p[g * HID + lane];
  buf[64 + lane] = sum_p[g * HID + lane] / c;
  float mx = dec_f(max_enc[g * HID + lane]);
  if (!isfinite(mx)) mx = 0.f;
  buf[128 + lane] = mx;
  __syncthreads();
  float a = fb1[lane];
  for (int k = 0; k < 192; ++k) a += buf[k] * fw1[k * 64 + lane];
  float mean = wave_sum64(a) * (1.f / 64.f);
  float d = a - mean;
  float var = wave_sum64(d * d) * (1.f / 64.f);
  float r = fmaxf(d * rsqrtf(var + 1e-5f) * flng[lane] + flnb[lane], 0.f);
  r1s[lane] = r;
  __syncthreads();
  if (lane < 32) {
    float a2 = fb2[lane];
    for (int k = 0; k < 64; ++k) a2 += r1s[k] * fw2[k * 32 + lane];
    r2s[lane] = fmaxf(a2, 0.f);
  }
  __syncthreads();
  if (lane < 16) {
    float a3 = pb1[lane];
    for (int k = 0; k < 32; ++k) a3 += r2s[k] * pw1[k * 16 + lane];
    r3s[lane] = fmaxf(a3, 0.f);
  }
  __syncthreads();
  if (lane == 0) {
    float a4 = pb2[0];
    for (int k = 0; k < 16; ++k) a4 += r3s[k] * pw2[k];
    out[g] = a4;
  }
}

// ---------- launch ----------

extern "C" void kernel_launch(void* const* d_in, const int* in_sizes, int n_in,
                              void* d_out, int out_size, void* d_ws, size_t ws_size,
                              hipStream_t stream) {
  const float* x = (const float*)d_in[0];
  const float* gf = (const float*)d_in[1];
  const int* ei = (const int*)d_in[2];
  const int* batch = (const int*)d_in[3];
  const float* in_w = (const float*)d_in[4];
  const float* in_b = (const float*)d_in[5];
  const float* in_ln_g = (const float*)d_in[6];
  const float* in_ln_b = (const float*)d_in[7];
  const float* gin_eps = (const float*)d_in[8];
  const float* gin_w1 = (const float*)d_in[9];
  const float* gin_b1 = (const float*)d_in[10];
  const float* gin_bn_g = (const float*)d_in[11];
  const float* gin_bn_b = (const float*)d_in[12];
  const float* gin_bn_m = (const float*)d_in[13];
  const float* gin_bn_v = (const float*)d_in[14];
  const float* gin_w2 = (const float*)d_in[15];
  const float* gin_b2 = (const float*)d_in[16];
  const float* gin_ln_g = (const float*)d_in[17];
  const float* gin_ln_b = (const float*)d_in[18];
  const float* gat_w = (const float*)d_in[19];
  const float* gat_asrc = (const float*)d_in[20];
  const float* gat_adst = (const float*)d_in[21];
  const float* gat_bias = (const float*)d_in[22];
  const float* gat_ln_g = (const float*)d_in[23];
  const float* gat_ln_b = (const float*)d_in[24];
  const float* fus_w1 = (const float*)d_in[25];
  const float* fus_b1 = (const float*)d_in[26];
  const float* fus_ln_g = (const float*)d_in[27];
  const float* fus_ln_b = (const float*)d_in[28];
  const float* fus_w2 = (const float*)d_in[29];
  const float* fus_b2 = (const float*)d_in[30];
  const float* pred_w1 = (const float*)d_in[31];
  const float* pred_b1 = (const float*)d_in[32];
  const float* pred_w2 = (const float*)d_in[33];
  const float* pred_b2 = (const float*)d_in[34];
  float* out = (float*)d_out;

  const int* src = ei;
  const int* dst = ei + N_EDGES;

  char* w = (char*)d_ws;
  float* h = (float*)w;        w += (size_t)N_NODES * HID * 4;
  float* agg = (float*)w;      w += (size_t)N_NODES * HID * 4;   // also GAT out buffer
  float* xp = (float*)w;       w += (size_t)N_NODES * HID * 4;
  float* asr = (float*)w;      w += (size_t)N_NODES * HEADS * 4;
  float* adt = (float*)w;      w += (size_t)N_NODES * HEADS * 4;
  unsigned* menc = (unsigned*)w; w += (size_t)N_NODES * HEADS * 4;
  float* ssum = (float*)w;     w += (size_t)N_NODES * HEADS * 4;
  float* add_p = (float*)w;    w += (size_t)N_GRAPHS * HID * 4;
  float* sum_p = (float*)w;    w += (size_t)N_GRAPHS * HID * 4;
  unsigned* max_enc = (unsigned*)w; w += (size_t)N_GRAPHS * HID * 4;
  float* cnt = (float*)w;      w += (size_t)N_GRAPHS * 4;

  dim3 blk(256);
  int nwb = (N_NODES + 3) / 4;          // node-wave blocks (4 waves/block)
  int ewb = (N_EDGES + 3) / 4;          // edge-wave blocks
  int ehb = (N_EDGES * HEADS + 255) / 256;
  int nhb = (N_NODES * HEADS + 255) / 256;

  k_pool_init<<<(N_GRAPHS * HID + 255) / 256, blk, 0, stream>>>(add_p, sum_p, max_enc, cnt);
  k_input<<<nwb, blk, 0, stream>>>(x, gf, batch, in_w, in_b, in_ln_g, in_ln_b, h);

  for (int i = 0; i < 2; ++i) {
    k_zero<<<(N_NODES * HID + 255) / 256, blk, 0, stream>>>(agg, N_NODES * HID);
    k_gin_agg<<<ewb, blk, 0, stream>>>(src, dst, h, agg);
    k_gin_node<<<nwb, blk, 0, stream>>>(agg, gin_eps + i,
        gin_w1 + (size_t)i * 64 * 128, gin_b1 + i * 128,
        gin_bn_g + i * 128, gin_bn_b + i * 128, gin_bn_m + i * 128, gin_bn_v + i * 128,
        gin_w2 + (size_t)i * 128 * 64, gin_b2 + i * 64,
        gin_ln_g + i * 64, gin_ln_b + i * 64, h);
  }

  k_pool_add<<<nwb, blk, 0, stream>>>(h, batch, add_p, cnt);

  for (int i = 0; i < 2; ++i) {
    k_gat_pre<<<nwb, blk, 0, stream>>>(h, gat_w + (size_t)i * 64 * 64,
        gat_asrc + i * HEADS * HEAD_DIM, gat_adst + i * HEADS * HEAD_DIM,
        xp, asr, adt, menc);
    k_gat_emax<<<ehb, blk, 0, stream>>>(src, dst, asr, adt, menc);
    k_gat_sinit<<<nhb, blk, 0, stream>>>(asr, adt, menc, ssum);
    k_gat_esum<<<ehb, blk, 0, stream>>>(src, dst, asr, adt, menc, ssum);
    k_gat_oinit<<<nwb, blk, 0, stream>>>(xp, asr, adt, menc, ssum, agg);
    k_gat_eagg<<<ewb, blk, 0, stream>>>(src, dst, xp, asr, adt, menc, ssum, agg);
    k_gat_fin<<<nwb, blk, 0, stream>>>(agg, gat_bias + i * 64,
        gat_ln_g + i * 64, gat_ln_b + i * 64, h);
  }

  k_pool_meanmax<<<nwb, blk, 0, stream>>>(h, batch, sum_p, max_enc);

  k_final<<<N_GRAPHS, 64, 0, stream>>>(add_p, sum_p, max_enc, cnt,
      fus_w1, fus_b1, fus_ln_g, fus_ln_b, fus_w2, fus_b2,
      pred_w1, pred_b1, pred_w2, pred_b2, out);
}

// Round 2
// 1474.641 us; speedup vs baseline: 1.6327x; 1.6327x over previous
//
#include <hip/hip_runtime.h>
#include <math.h>

#define N_NODES 100000
#define N_EDGES 1200000
#define N_GRAPHS 512
#define HID 64
#define HEADS 4
#define HEAD_DIM 16
#define IN_DIM 24
#define GDIM 10
#define NB_SCAN 391   // ceil(N_NODES/256)

// ---------- helpers ----------

__device__ __forceinline__ float wave_sum64(float v) {
#pragma unroll
  for (int m = 32; m >= 1; m >>= 1) v += __shfl_xor(v, m, 64);
  return v;
}

__device__ __forceinline__ float head_sum16(float v) {
#pragma unroll
  for (int m = 8; m >= 1; m >>= 1) v += __shfl_xor(v, m, 64);
  return v;
}

__device__ __forceinline__ unsigned enc_f(float f) {
  unsigned u = __float_as_uint(f);
  return (u & 0x80000000u) ? ~u : (u | 0x80000000u);
}
__device__ __forceinline__ float dec_f(unsigned u) {
  unsigned v = (u & 0x80000000u) ? (u & 0x7FFFFFFFu) : ~u;
  return __uint_as_float(v);
}

__device__ __forceinline__ float lrelu02(float x) {
  return x > 0.f ? x : 0.2f * x;
}

// ---------- CSR build ----------

__global__ void k_zero_int(int* __restrict__ p, int n) {
  int i = blockIdx.x * blockDim.x + threadIdx.x;
  if (i < n) p[i] = 0;
}

__global__ void k_hist(const int* __restrict__ dst, int* __restrict__ deg) {
  int e = blockIdx.x * blockDim.x + threadIdx.x;
  if (e < N_EDGES) atomicAdd(&deg[dst[e]], 1);
}

__global__ void k_blocksum(const int* __restrict__ deg, int* __restrict__ bsum) {
  __shared__ int s[256];
  int i = blockIdx.x * 256 + threadIdx.x;
  s[threadIdx.x] = (i < N_NODES) ? deg[i] : 0;
  __syncthreads();
  for (int off = 128; off >= 1; off >>= 1) {
    if (threadIdx.x < off) s[threadIdx.x] += s[threadIdx.x + off];
    __syncthreads();
  }
  if (threadIdx.x == 0) bsum[blockIdx.x] = s[0];
}

// single block, 512 threads: exclusive scan of bsum[NB_SCAN] -> boff
__global__ void k_scanb(const int* __restrict__ bsum, int* __restrict__ boff) {
  __shared__ int s[512];
  int tid = threadIdx.x;
  int v = (tid < NB_SCAN) ? bsum[tid] : 0;
  s[tid] = v;
  __syncthreads();
  for (int off = 1; off < 512; off <<= 1) {
    int t = (tid >= off) ? s[tid - off] : 0;
    __syncthreads();
    s[tid] += t;
    __syncthreads();
  }
  if (tid < NB_SCAN) boff[tid] = s[tid] - v;  // exclusive
}

__global__ void k_offsets(const int* __restrict__ deg, const int* __restrict__ boff,
                          int* __restrict__ ptr, int* __restrict__ cur) {
  __shared__ int s[256];
  int i = blockIdx.x * 256 + threadIdx.x;
  int v = (i < N_NODES) ? deg[i] : 0;
  s[threadIdx.x] = v;
  __syncthreads();
  for (int off = 1; off < 256; off <<= 1) {
    int t = (threadIdx.x >= off) ? s[threadIdx.x - off] : 0;
    __syncthreads();
    s[threadIdx.x] += t;
    __syncthreads();
  }
  if (i < N_NODES) {
    int p = boff[blockIdx.x] + s[threadIdx.x] - v;  // exclusive start
    ptr[i] = p;
    cur[i] = p;
  }
}

__global__ void k_scatter(const int* __restrict__ src, const int* __restrict__ dst,
                          int* __restrict__ cur, int* __restrict__ csr_src) {
  int e = blockIdx.x * blockDim.x + threadIdx.x;
  if (e < N_EDGES) {
    int pos = atomicAdd(&cur[dst[e]], 1);
    csr_src[pos] = src[e];
  }
}

// ---------- graph NN kernels ----------

__global__ void k_pool_init(float* __restrict__ add_p, float* __restrict__ sum_p,
                            unsigned* __restrict__ max_enc, float* __restrict__ cnt) {
  int i = blockIdx.x * blockDim.x + threadIdx.x;
  if (i < N_GRAPHS * HID) {
    add_p[i] = 0.f;
    sum_p[i] = 0.f;
    max_enc[i] = enc_f(-INFINITY);
  }
  if (i < N_GRAPHS) cnt[i] = 0.f;
}

// input projection + LN + relu. one wave per node, lane = feature.
__global__ void k_input(const float* __restrict__ x, const float* __restrict__ gf,
                        const int* __restrict__ batch,
                        const float* __restrict__ w, const float* __restrict__ b,
                        const float* __restrict__ lng, const float* __restrict__ lnb,
                        float* __restrict__ h) {
  int n = (blockIdx.x * blockDim.x + threadIdx.x) >> 6;
  int lane = threadIdx.x & 63;
  if (n >= N_NODES) return;
  int g = batch[n];
  float feat = 0.f;
  if (lane < IN_DIM) feat = x[n * IN_DIM + lane];
  else if (lane < IN_DIM + GDIM) feat = gf[g * GDIM + (lane - IN_DIM)];
  float acc = b[lane];
#pragma unroll
  for (int k = 0; k < IN_DIM + GDIM; ++k) {
    float fk = __shfl(feat, k, 64);
    acc += fk * w[k * HID + lane];
  }
  float mean = wave_sum64(acc) * (1.f / 64.f);
  float d = acc - mean;
  float var = wave_sum64(d * d) * (1.f / 64.f);
  float v = d * rsqrtf(var + 1e-5f) * lng[lane] + lnb[lane];
  h[n * HID + lane] = fmaxf(v, 0.f);
}

// Fused GIN layer: gather-sum over in-edges + MLP + LN + residual.
// Reads h_in (all rows), writes h_out (own row). Optional add-pool epilogue.
__global__ void k_gin_fused(const int* __restrict__ ptr, const int* __restrict__ deg,
                            const int* __restrict__ csr_src,
                            const float* __restrict__ h_in, float* __restrict__ h_out,
                            const float* __restrict__ eps_p,
                            const float* __restrict__ w1, const float* __restrict__ b1,
                            const float* __restrict__ bng, const float* __restrict__ bnb,
                            const float* __restrict__ bnm, const float* __restrict__ bnv,
                            const float* __restrict__ w2, const float* __restrict__ b2,
                            const float* __restrict__ lng, const float* __restrict__ lnb,
                            int do_pool, const int* __restrict__ batch,
                            float* __restrict__ add_p, float* __restrict__ cnt) {
  int n = (blockIdx.x * blockDim.x + threadIdx.x) >> 6;
  int lane = threadIdx.x & 63;
  if (n >= N_NODES) return;
  int base = ptr[n], dg = deg[n];
  float hj = h_in[(size_t)n * HID + lane];
  float agg = 0.f;
  int s_next = (dg > 0) ? csr_src[base] : 0;
  for (int it = 0; it < dg; ++it) {
    int s = s_next;
    if (it + 1 < dg) s_next = csr_src[base + it + 1];
    agg += h_in[(size_t)s * HID + lane];
  }
  float z = (1.f + eps_p[0]) * hj + agg;
  float a0 = b1[lane], a1 = b1[lane + 64];
  for (int k = 0; k < 64; ++k) {
    float zk = __shfl(z, k, 64);
    a0 += zk * w1[k * 128 + lane];
    a1 += zk * w1[k * 128 + 64 + lane];
  }
  a0 = (a0 - bnm[lane]) * rsqrtf(bnv[lane] + 1e-5f) * bng[lane] + bnb[lane];
  a1 = (a1 - bnm[lane + 64]) * rsqrtf(bnv[lane + 64] + 1e-5f) * bng[lane + 64] + bnb[lane + 64];
  a0 = fmaxf(a0, 0.f);
  a1 = fmaxf(a1, 0.f);
  float o = b2[lane];
  for (int k = 0; k < 64; ++k) {
    float r0 = __shfl(a0, k, 64);
    float r1 = __shfl(a1, k, 64);
    o += r0 * w2[k * 64 + lane] + r1 * w2[(64 + k) * 64 + lane];
  }
  float mean = wave_sum64(o) * (1.f / 64.f);
  float d = o - mean;
  float var = wave_sum64(d * d) * (1.f / 64.f);
  float v = d * rsqrtf(var + 1e-5f) * lng[lane] + lnb[lane];
  float hnew = fmaxf(v, 0.f) + hj;
  h_out[(size_t)n * HID + lane] = hnew;
  if (do_pool) {
    int g = batch[n];
    atomicAdd(&add_p[g * HID + lane], hnew);
    if (lane == 0) atomicAdd(&cnt[g], 1.f);
  }
}

// GAT per-node precompute: xp = h @ W, per-head asr/adt dots.
__global__ void k_gat_pre(const float* __restrict__ h, const float* __restrict__ w,
                          const float* __restrict__ asrc, const float* __restrict__ adst,
                          float* __restrict__ xp, float* __restrict__ asr,
                          float* __restrict__ adt) {
  int n = (blockIdx.x * blockDim.x + threadIdx.x) >> 6;
  int lane = threadIdx.x & 63;
  if (n >= N_NODES) return;
  float hj = h[(size_t)n * HID + lane];
  float p = 0.f;
  for (int k = 0; k < 64; ++k) {
    float hk = __shfl(hj, k, 64);
    p += hk * w[k * 64 + lane];
  }
  xp[(size_t)n * HID + lane] = p;
  int head = lane >> 4;
  float as = head_sum16(p * asrc[head * HEAD_DIM + (lane & 15)]);
  float ad = head_sum16(p * adst[head * HEAD_DIM + (lane & 15)]);
  if ((lane & 15) == 0) {
    asr[n * HEADS + head] = as;
    adt[n * HEADS + head] = ad;
  }
}

// Fused GAT aggregation: softmax over in-edges (+self-loop) per head,
// weighted gather of xp rows, +bias, LN, elu, residual (in place on h).
// Optional mean/max pool epilogue.
__global__ void k_gat_agg(const int* __restrict__ ptr, const int* __restrict__ deg,
                          const int* __restrict__ csr_src,
                          const float* __restrict__ xp, const float* __restrict__ asr,
                          const float* __restrict__ adt,
                          const float* __restrict__ bias,
                          const float* __restrict__ lng, const float* __restrict__ lnb,
                          float* __restrict__ h,
                          int do_pool, const int* __restrict__ batch,
                          float* __restrict__ sum_p, unsigned* __restrict__ max_enc) {
  int n = (blockIdx.x * blockDim.x + threadIdx.x) >> 6;
  int lane = threadIdx.x & 63;
  if (n >= N_NODES) return;
  int head = lane >> 4;
  int base = ptr[n], dg = deg[n];
  float adt_d = adt[n * HEADS + head];
  float el = lrelu02(asr[n * HEADS + head] + adt_d);  // self-loop logit
  // pass 1: max over in-edges
  float m = el;
  int s_next = (dg > 0) ? csr_src[base] : 0;
  for (int it = 0; it < dg; ++it) {
    int s = s_next;
    if (it + 1 < dg) s_next = csr_src[base + it + 1];
    float e = lrelu02(asr[s * HEADS + head] + adt_d);
    m = fmaxf(m, e);
  }
  // pass 2: unnormalized weighted sum + partition
  float psum = __expf(el - m);
  float o = psum * xp[(size_t)n * HID + lane];
  s_next = (dg > 0) ? csr_src[base] : 0;
  for (int it = 0; it < dg; ++it) {
    int s = s_next;
    if (it + 1 < dg) s_next = csr_src[base + it + 1];
    float e = lrelu02(asr[s * HEADS + head] + adt_d);
    float p = __expf(e - m);
    psum += p;
    o += p * xp[(size_t)s * HID + lane];
  }
  o = o / psum + bias[lane];
  float mean = wave_sum64(o) * (1.f / 64.f);
  float d = o - mean;
  float var = wave_sum64(d * d) * (1.f / 64.f);
  float v = d * rsqrtf(var + 1e-5f) * lng[lane] + lnb[lane];
  float e2 = v > 0.f ? v : expm1f(v);
  float hnew = e2 + h[(size_t)n * HID + lane];
  h[(size_t)n * HID + lane] = hnew;
  if (do_pool) {
    int g = batch[n];
    atomicAdd(&sum_p[g * HID + lane], hnew);
    atomicMax(&max_enc[g * HID + lane], enc_f(hnew));
  }
}

// final per-graph MLP. one 64-thread block (one wave) per graph.
__global__ void k_final(const float* __restrict__ add_p, const float* __restrict__ sum_p,
                        const unsigned* __restrict__ max_enc, const float* __restrict__ cnt,
                        const float* __restrict__ fw1, const float* __restrict__ fb1,
                        const float* __restrict__ flng, const float* __restrict__ flnb,
                        const float* __restrict__ fw2, const float* __restrict__ fb2,
                        const float* __restrict__ pw1, const float* __restrict__ pb1,
                        const float* __restrict__ pw2, const float* __restrict__ pb2,
                        float* __restrict__ out) {
  __shared__ float buf[192];
  __shared__ float r1s[64];
  __shared__ float r2s[32];
  __shared__ float r3s[16];
  int g = blockIdx.x;
  int lane = threadIdx.x;
  float c = fmaxf(cnt[g], 1.f);
  buf[lane] = add_p[g * HID + lane];
  buf[64 + lane] = sum_p[g * HID + lane] / c;
  float mx = dec_f(max_enc[g * HID + lane]);
  if (!isfinite(mx)) mx = 0.f;
  buf[128 + lane] = mx;
  __syncthreads();
  float a = fb1[lane];
  for (int k = 0; k < 192; ++k) a += buf[k] * fw1[k * 64 + lane];
  float mean = wave_sum64(a) * (1.f / 64.f);
  float d = a - mean;
  float var = wave_sum64(d * d) * (1.f / 64.f);
  float r = fmaxf(d * rsqrtf(var + 1e-5f) * flng[lane] + flnb[lane], 0.f);
  r1s[lane] = r;
  __syncthreads();
  if (lane < 32) {
    float a2 = fb2[lane];
    for (int k = 0; k < 64; ++k) a2 += r1s[k] * fw2[k * 32 + lane];
    r2s[lane] = fmaxf(a2, 0.f);
  }
  __syncthreads();
  if (lane < 16) {
    float a3 = pb1[lane];
    for (int k = 0; k < 32; ++k) a3 += r2s[k] * pw1[k * 16 + lane];
    r3s[lane] = fmaxf(a3, 0.f);
  }
  __syncthreads();
  if (lane == 0) {
    float a4 = pb2[0];
    for (int k = 0; k < 16; ++k) a4 += r3s[k] * pw2[k];
    out[g] = a4;
  }
}

// ---------- launch ----------

extern "C" void kernel_launch(void* const* d_in, const int* in_sizes, int n_in,
                              void* d_out, int out_size, void* d_ws, size_t ws_size,
                              hipStream_t stream) {
  const float* x = (const float*)d_in[0];
  const float* gf = (const float*)d_in[1];
  const int* ei = (const int*)d_in[2];
  const int* batch = (const int*)d_in[3];
  const float* in_w = (const float*)d_in[4];
  const float* in_b = (const float*)d_in[5];
  const float* in_ln_g = (const float*)d_in[6];
  const float* in_ln_b = (const float*)d_in[7];
  const float* gin_eps = (const float*)d_in[8];
  const float* gin_w1 = (const float*)d_in[9];
  const float* gin_b1 = (const float*)d_in[10];
  const float* gin_bn_g = (const float*)d_in[11];
  const float* gin_bn_b = (const float*)d_in[12];
  const float* gin_bn_m = (const float*)d_in[13];
  const float* gin_bn_v = (const float*)d_in[14];
  const float* gin_w2 = (const float*)d_in[15];
  const float* gin_b2 = (const float*)d_in[16];
  const float* gin_ln_g = (const float*)d_in[17];
  const float* gin_ln_b = (const float*)d_in[18];
  const float* gat_w = (const float*)d_in[19];
  const float* gat_asrc = (const float*)d_in[20];
  const float* gat_adst = (const float*)d_in[21];
  const float* gat_bias = (const float*)d_in[22];
  const float* gat_ln_g = (const float*)d_in[23];
  const float* gat_ln_b = (const float*)d_in[24];
  const float* fus_w1 = (const float*)d_in[25];
  const float* fus_b1 = (const float*)d_in[26];
  const float* fus_ln_g = (const float*)d_in[27];
  const float* fus_ln_b = (const float*)d_in[28];
  const float* fus_w2 = (const float*)d_in[29];
  const float* fus_b2 = (const float*)d_in[30];
  const float* pred_w1 = (const float*)d_in[31];
  const float* pred_b1 = (const float*)d_in[32];
  const float* pred_w2 = (const float*)d_in[33];
  const float* pred_b2 = (const float*)d_in[34];
  float* out = (float*)d_out;

  const int* src = ei;
  const int* dst = ei + N_EDGES;

  char* w = (char*)d_ws;
  float* hA = (float*)w;       w += (size_t)N_NODES * HID * 4;
  float* hB = (float*)w;       w += (size_t)N_NODES * HID * 4;   // GIN ping-pong; GAT xp
  float* asr = (float*)w;      w += (size_t)N_NODES * HEADS * 4;
  float* adt = (float*)w;      w += (size_t)N_NODES * HEADS * 4;
  int* deg = (int*)w;          w += (size_t)N_NODES * 4;
  int* ptr = (int*)w;          w += (size_t)N_NODES * 4;
  int* cur = (int*)w;          w += (size_t)N_NODES * 4;
  int* csr_src = (int*)w;      w += (size_t)N_EDGES * 4;
  int* bsum = (int*)w;         w += 512 * 4;
  int* boff = (int*)w;         w += 512 * 4;
  float* add_p = (float*)w;    w += (size_t)N_GRAPHS * HID * 4;
  float* sum_p = (float*)w;    w += (size_t)N_GRAPHS * HID * 4;
  unsigned* max_enc = (unsigned*)w; w += (size_t)N_GRAPHS * HID * 4;
  float* cnt = (float*)w;      w += (size_t)N_GRAPHS * 4;

  dim3 blk(256);
  int nwb = (N_NODES + 3) / 4;            // node-wave blocks (4 waves/block)
  int eb = (N_EDGES + 255) / 256;         // edge-thread blocks
  int nb256 = (N_NODES + 255) / 256;

  // --- CSR build (dst-bucketed) ---
  k_zero_int<<<nb256, blk, 0, stream>>>(deg, N_NODES);
  k_hist<<<eb, blk, 0, stream>>>(dst, deg);
  k_blocksum<<<NB_SCAN, blk, 0, stream>>>(deg, bsum);
  k_scanb<<<1, 512, 0, stream>>>(bsum, boff);
  k_offsets<<<NB_SCAN, blk, 0, stream>>>(deg, boff, ptr, cur);
  k_scatter<<<eb, blk, 0, stream>>>(src, dst, cur, csr_src);

  k_pool_init<<<(N_GRAPHS * HID + 255) / 256, blk, 0, stream>>>(add_p, sum_p, max_enc, cnt);
  k_input<<<nwb, blk, 0, stream>>>(x, gf, batch, in_w, in_b, in_ln_g, in_ln_b, hA);

  // --- GIN stack (ping-pong hA -> hB -> hA) ---
  for (int i = 0; i < 2; ++i) {
    const float* hin = (i == 0) ? hA : hB;
    float* hout = (i == 0) ? hB : hA;
    k_gin_fused<<<nwb, blk, 0, stream>>>(ptr, deg, csr_src, hin, hout, gin_eps + i,
        gin_w1 + (size_t)i * 64 * 128, gin_b1 + i * 128,
        gin_bn_g + i * 128, gin_bn_b + i * 128, gin_bn_m + i * 128, gin_bn_v + i * 128,
        gin_w2 + (size_t)i * 128 * 64, gin_b2 + i * 64,
        gin_ln_g + i * 64, gin_ln_b + i * 64,
        (i == 1) ? 1 : 0, batch, add_p, cnt);
  }

  // --- GAT stack (in place on hA; hB reused as xp) ---
  for (int i = 0; i < 2; ++i) {
    k_gat_pre<<<nwb, blk, 0, stream>>>(hA, gat_w + (size_t)i * 64 * 64,
        gat_asrc + i * HEADS * HEAD_DIM, gat_adst + i * HEADS * HEAD_DIM,
        hB, asr, adt);
    k_gat_agg<<<nwb, blk, 0, stream>>>(ptr, deg, csr_src, hB, asr, adt,
        gat_bias + i * 64, gat_ln_g + i * 64, gat_ln_b + i * 64, hA,
        (i == 1) ? 1 : 0, batch, sum_p, max_enc);
  }

  k_final<<<N_GRAPHS, 64, 0, stream>>>(add_p, sum_p, max_enc, cnt,
      fus_w1, fus_b1, fus_ln_g, fus_ln_b, fus_w2, fus_b2,
      pred_w1, pred_b1, pred_w2, pred_b2, out);
}

// Round 3
// 1309.408 us; speedup vs baseline: 1.8388x; 1.1262x over previous
//
#include <hip/hip_runtime.h>
#include <math.h>

#define N_NODES 100000
#define N_EDGES 1200000
#define N_GRAPHS 512
#define HID 64
#define HEADS 4
#define HEAD_DIM 16
#define IN_DIM 24
#define GDIM 10
#define NB_SCAN 391   // ceil(N_NODES/256)

// ---------- helpers ----------

__device__ __forceinline__ float wave_sum64(float v) {
#pragma unroll
  for (int m = 32; m >= 1; m >>= 1) v += __shfl_xor(v, m, 64);
  return v;
}

__device__ __forceinline__ float head_sum16(float v) {
#pragma unroll
  for (int m = 8; m >= 1; m >>= 1) v += __shfl_xor(v, m, 64);
  return v;
}

__device__ __forceinline__ unsigned enc_f(float f) {
  unsigned u = __float_as_uint(f);
  return (u & 0x80000000u) ? ~u : (u | 0x80000000u);
}
__device__ __forceinline__ float dec_f(unsigned u) {
  unsigned v = (u & 0x80000000u) ? (u & 0x7FFFFFFFu) : ~u;
  return __uint_as_float(v);
}

__device__ __forceinline__ float lrelu02(float x) {
  return x > 0.f ? x : 0.2f * x;
}

// ---------- CSR build ----------

__global__ void k_zero_int(int* __restrict__ p, int n) {
  int i = blockIdx.x * blockDim.x + threadIdx.x;
  if (i < n) p[i] = 0;
}

__global__ void k_hist(const int* __restrict__ dst, int* __restrict__ deg) {
  int e = blockIdx.x * blockDim.x + threadIdx.x;
  if (e < N_EDGES) atomicAdd(&deg[dst[e]], 1);
}

__global__ void k_blocksum(const int* __restrict__ deg, int* __restrict__ bsum) {
  __shared__ int s[256];
  int i = blockIdx.x * 256 + threadIdx.x;
  s[threadIdx.x] = (i < N_NODES) ? deg[i] : 0;
  __syncthreads();
  for (int off = 128; off >= 1; off >>= 1) {
    if (threadIdx.x < off) s[threadIdx.x] += s[threadIdx.x + off];
    __syncthreads();
  }
  if (threadIdx.x == 0) bsum[blockIdx.x] = s[0];
}

// single block, 512 threads: exclusive scan of bsum[NB_SCAN] -> boff
__global__ void k_scanb(const int* __restrict__ bsum, int* __restrict__ boff) {
  __shared__ int s[512];
  int tid = threadIdx.x;
  int v = (tid < NB_SCAN) ? bsum[tid] : 0;
  s[tid] = v;
  __syncthreads();
  for (int off = 1; off < 512; off <<= 1) {
    int t = (tid >= off) ? s[tid - off] : 0;
    __syncthreads();
    s[tid] += t;
    __syncthreads();
  }
  if (tid < NB_SCAN) boff[tid] = s[tid] - v;  // exclusive
}

__global__ void k_offsets(const int* __restrict__ deg, const int* __restrict__ boff,
                          int* __restrict__ ptr, int* __restrict__ cur) {
  __shared__ int s[256];
  int i = blockIdx.x * 256 + threadIdx.x;
  int v = (i < N_NODES) ? deg[i] : 0;
  s[threadIdx.x] = v;
  __syncthreads();
  for (int off = 1; off < 256; off <<= 1) {
    int t = (threadIdx.x >= off) ? s[threadIdx.x - off] : 0;
    __syncthreads();
    s[threadIdx.x] += t;
    __syncthreads();
  }
  if (i < N_NODES) {
    int p = boff[blockIdx.x] + s[threadIdx.x] - v;  // exclusive start
    ptr[i] = p;
    cur[i] = p;
  }
}

__global__ void k_scatter(const int* __restrict__ src, const int* __restrict__ dst,
                          int* __restrict__ cur, int* __restrict__ csr_src) {
  int e = blockIdx.x * blockDim.x + threadIdx.x;
  if (e < N_EDGES) {
    int pos = atomicAdd(&cur[dst[e]], 1);
    csr_src[pos] = src[e];
  }
}

// ---------- graph NN kernels ----------

__global__ void k_pool_init(float* __restrict__ add_p, float* __restrict__ sum_p,
                            unsigned* __restrict__ max_enc, float* __restrict__ cnt) {
  int i = blockIdx.x * blockDim.x + threadIdx.x;
  if (i < N_GRAPHS * HID) {
    add_p[i] = 0.f;
    sum_p[i] = 0.f;
    max_enc[i] = enc_f(-INFINITY);
  }
  if (i < N_GRAPHS) cnt[i] = 0.f;
}

// input projection + LN + relu. one wave per node, lane = feature.
__global__ void k_input(const float* __restrict__ x, const float* __restrict__ gf,
                        const int* __restrict__ batch,
                        const float* __restrict__ w, const float* __restrict__ b,
                        const float* __restrict__ lng, const float* __restrict__ lnb,
                        float* __restrict__ h) {
  int n = (blockIdx.x * blockDim.x + threadIdx.x) >> 6;
  int lane = threadIdx.x & 63;
  if (n >= N_NODES) return;
  int g = batch[n];
  float feat = 0.f;
  if (lane < IN_DIM) feat = x[n * IN_DIM + lane];
  else if (lane < IN_DIM + GDIM) feat = gf[g * GDIM + (lane - IN_DIM)];
  float acc = b[lane];
#pragma unroll
  for (int k = 0; k < IN_DIM + GDIM; ++k) {
    float fk = __shfl(feat, k, 64);
    acc += fk * w[k * HID + lane];
  }
  float mean = wave_sum64(acc) * (1.f / 64.f);
  float d = acc - mean;
  float var = wave_sum64(d * d) * (1.f / 64.f);
  float v = d * rsqrtf(var + 1e-5f) * lng[lane] + lnb[lane];
  h[n * HID + lane] = fmaxf(v, 0.f);
}

// Fused GIN layer: gather-sum over in-edges + MLP + LN + residual.
// Indices are loaded cooperatively (one per lane) and broadcast via shfl so
// the row-gather loads are independent; x4 unroll keeps >=4 loads in flight.
__global__ void k_gin_fused(const int* __restrict__ ptr, const int* __restrict__ deg,
                            const int* __restrict__ csr_src,
                            const float* __restrict__ h_in, float* __restrict__ h_out,
                            const float* __restrict__ eps_p,
                            const float* __restrict__ w1, const float* __restrict__ b1,
                            const float* __restrict__ bng, const float* __restrict__ bnb,
                            const float* __restrict__ bnm, const float* __restrict__ bnv,
                            const float* __restrict__ w2, const float* __restrict__ b2,
                            const float* __restrict__ lng, const float* __restrict__ lnb,
                            int do_pool, const int* __restrict__ batch,
                            float* __restrict__ add_p, float* __restrict__ cnt) {
  int n = (blockIdx.x * blockDim.x + threadIdx.x) >> 6;
  int lane = threadIdx.x & 63;
  if (n >= N_NODES) return;
  int base = ptr[n], dg = deg[n];
  float hj = h_in[(size_t)n * HID + lane];
  float agg = 0.f;
  for (int c = 0; c < dg; c += 64) {
    int rem = dg - c; if (rem > 64) rem = 64;
    int idx = (lane < rem) ? csr_src[base + c + lane] : 0;
    int it = 0;
    for (; it + 4 <= rem; it += 4) {
      int s0 = __shfl(idx, it, 64);
      int s1 = __shfl(idx, it + 1, 64);
      int s2 = __shfl(idx, it + 2, 64);
      int s3 = __shfl(idx, it + 3, 64);
      float v0 = h_in[(size_t)s0 * HID + lane];
      float v1 = h_in[(size_t)s1 * HID + lane];
      float v2 = h_in[(size_t)s2 * HID + lane];
      float v3 = h_in[(size_t)s3 * HID + lane];
      agg += (v0 + v1) + (v2 + v3);
    }
    for (; it < rem; ++it) {
      int s = __shfl(idx, it, 64);
      agg += h_in[(size_t)s * HID + lane];
    }
  }
  float z = (1.f + eps_p[0]) * hj + agg;
  float a0 = b1[lane], a1 = b1[lane + 64];
  for (int k = 0; k < 64; ++k) {
    float zk = __shfl(z, k, 64);
    a0 += zk * w1[k * 128 + lane];
    a1 += zk * w1[k * 128 + 64 + lane];
  }
  a0 = (a0 - bnm[lane]) * rsqrtf(bnv[lane] + 1e-5f) * bng[lane] + bnb[lane];
  a1 = (a1 - bnm[lane + 64]) * rsqrtf(bnv[lane + 64] + 1e-5f) * bng[lane + 64] + bnb[lane + 64];
  a0 = fmaxf(a0, 0.f);
  a1 = fmaxf(a1, 0.f);
  float o = b2[lane];
  for (int k = 0; k < 64; ++k) {
    float r0 = __shfl(a0, k, 64);
    float r1 = __shfl(a1, k, 64);
    o += r0 * w2[k * 64 + lane] + r1 * w2[(64 + k) * 64 + lane];
  }
  float mean = wave_sum64(o) * (1.f / 64.f);
  float d = o - mean;
  float var = wave_sum64(d * d) * (1.f / 64.f);
  float v = d * rsqrtf(var + 1e-5f) * lng[lane] + lnb[lane];
  float hnew = fmaxf(v, 0.f) + hj;
  h_out[(size_t)n * HID + lane] = hnew;
  if (do_pool) {
    int g = batch[n];
    atomicAdd(&add_p[g * HID + lane], hnew);
    if (lane == 0) atomicAdd(&cnt[g], 1.f);
  }
}

// GAT per-node precompute: xp = h @ W, per-head asr/adt dots.
__global__ void k_gat_pre(const float* __restrict__ h, const float* __restrict__ w,
                          const float* __restrict__ asrc, const float* __restrict__ adst,
                          float* __restrict__ xp, float* __restrict__ asr,
                          float* __restrict__ adt) {
  int n = (blockIdx.x * blockDim.x + threadIdx.x) >> 6;
  int lane = threadIdx.x & 63;
  if (n >= N_NODES) return;
  float hj = h[(size_t)n * HID + lane];
  float p = 0.f;
  for (int k = 0; k < 64; ++k) {
    float hk = __shfl(hj, k, 64);
    p += hk * w[k * 64 + lane];
  }
  xp[(size_t)n * HID + lane] = p;
  int head = lane >> 4;
  float as = head_sum16(p * asrc[head * HEAD_DIM + (lane & 15)]);
  float ad = head_sum16(p * adst[head * HEAD_DIM + (lane & 15)]);
  if ((lane & 15) == 0) {
    asr[n * HEADS + head] = as;
    adt[n * HEADS + head] = ad;
  }
}

// Fused GAT aggregation.
// Pass A: online-softmax (m, sum) over in-edge logits, 16 edges in parallel
// per head (lane-strided), merged with a 16-lane shuffle reduce.
// Pass B: weighted gather of xp rows, x4 unrolled with shfl-broadcast indices.
__global__ void k_gat_agg(const int* __restrict__ ptr, const int* __restrict__ deg,
                          const int* __restrict__ csr_src,
                          const float* __restrict__ xp, const float* __restrict__ asr,
                          const float* __restrict__ adt,
                          const float* __restrict__ bias,
                          const float* __restrict__ lng, const float* __restrict__ lnb,
                          float* __restrict__ h,
                          int do_pool, const int* __restrict__ batch,
                          float* __restrict__ sum_p, unsigned* __restrict__ max_enc) {
  int n = (blockIdx.x * blockDim.x + threadIdx.x) >> 6;
  int lane = threadIdx.x & 63;
  if (n >= N_NODES) return;
  int head = lane >> 4, sub = lane & 15;
  int base = ptr[n], dg = deg[n];
  float adt_d = adt[n * HEADS + head];
  float el = lrelu02(asr[n * HEADS + head] + adt_d);  // self-loop logit
  int rem0 = dg < 64 ? dg : 64;
  int idx0 = (lane < rem0) ? csr_src[base + lane] : 0;  // chunk-0 cache
  // ---- pass A: per-lane online softmax partials over strided edges ----
  float pm = -1e30f, ps = 0.f;
  for (int c = 0; c < dg; c += 64) {
    int rem = dg - c; if (rem > 64) rem = 64;
    int idx = (c == 0) ? idx0 : ((lane < rem) ? csr_src[base + c + lane] : 0);
    for (int j = sub; j < rem; j += 16) {
      int s = __shfl(idx, j, 64);
      float e = lrelu02(asr[s * HEADS + head] + adt_d);
      float nm = fmaxf(pm, e);
      ps = ps * __expf(pm - nm) + __expf(e - nm);
      pm = nm;
    }
  }
#pragma unroll
  for (int msk = 1; msk <= 8; msk <<= 1) {
    float om = __shfl_xor(pm, msk, 64);
    float os = __shfl_xor(ps, msk, 64);
    float nm = fmaxf(pm, om);
    ps = ps * __expf(pm - nm) + os * __expf(om - nm);
    pm = nm;
  }
  float mfin = fmaxf(pm, el);
  float psum = ps * __expf(pm - mfin) + __expf(el - mfin);
  // ---- pass B: weighted gather ----
  float o = __expf(el - mfin) * xp[(size_t)n * HID + lane];
  for (int c = 0; c < dg; c += 64) {
    int rem = dg - c; if (rem > 64) rem = 64;
    int idx = (c == 0) ? idx0 : ((lane < rem) ? csr_src[base + c + lane] : 0);
    int it = 0;
    for (; it + 4 <= rem; it += 4) {
      int s0 = __shfl(idx, it, 64);
      int s1 = __shfl(idx, it + 1, 64);
      int s2 = __shfl(idx, it + 2, 64);
      int s3 = __shfl(idx, it + 3, 64);
      float q0 = asr[s0 * HEADS + head];
      float q1 = asr[s1 * HEADS + head];
      float q2 = asr[s2 * HEADS + head];
      float q3 = asr[s3 * HEADS + head];
      float x0 = xp[(size_t)s0 * HID + lane];
      float x1 = xp[(size_t)s1 * HID + lane];
      float x2 = xp[(size_t)s2 * HID + lane];
      float x3 = xp[(size_t)s3 * HID + lane];
      float p0 = __expf(lrelu02(q0 + adt_d) - mfin);
      float p1 = __expf(lrelu02(q1 + adt_d) - mfin);
      float p2 = __expf(lrelu02(q2 + adt_d) - mfin);
      float p3 = __expf(lrelu02(q3 + adt_d) - mfin);
      o += (p0 * x0 + p1 * x1) + (p2 * x2 + p3 * x3);
    }
    for (; it < rem; ++it) {
      int s = __shfl(idx, it, 64);
      float e = lrelu02(asr[s * HEADS + head] + adt_d);
      o += __expf(e - mfin) * xp[(size_t)s * HID + lane];
    }
  }
  o = o / psum + bias[lane];
  float mean = wave_sum64(o) * (1.f / 64.f);
  float d = o - mean;
  float var = wave_sum64(d * d) * (1.f / 64.f);
  float v = d * rsqrtf(var + 1e-5f) * lng[lane] + lnb[lane];
  float e2 = v > 0.f ? v : expm1f(v);
  float hnew = e2 + h[(size_t)n * HID + lane];
  h[(size_t)n * HID + lane] = hnew;
  if (do_pool) {
    int g = batch[n];
    atomicAdd(&sum_p[g * HID + lane], hnew);
    atomicMax(&max_enc[g * HID + lane], enc_f(hnew));
  }
}

// final per-graph MLP. one 64-thread block (one wave) per graph.
__global__ void k_final(const float* __restrict__ add_p, const float* __restrict__ sum_p,
                        const unsigned* __restrict__ max_enc, const float* __restrict__ cnt,
                        const float* __restrict__ fw1, const float* __restrict__ fb1,
                        const float* __restrict__ flng, const float* __restrict__ flnb,
                        const float* __restrict__ fw2, const float* __restrict__ fb2,
                        const float* __restrict__ pw1, const float* __restrict__ pb1,
                        const float* __restrict__ pw2, const float* __restrict__ pb2,
                        float* __restrict__ out) {
  __shared__ float buf[192];
  __shared__ float r1s[64];
  __shared__ float r2s[32];
  __shared__ float r3s[16];
  int g = blockIdx.x;
  int lane = threadIdx.x;
  float c = fmaxf(cnt[g], 1.f);
  buf[lane] = add_p[g * HID + lane];
  buf[64 + lane] = sum_p[g * HID + lane] / c;
  float mx = dec_f(max_enc[g * HID + lane]);
  if (!isfinite(mx)) mx = 0.f;
  buf[128 + lane] = mx;
  __syncthreads();
  float a = fb1[lane];
  for (int k = 0; k < 192; ++k) a += buf[k] * fw1[k * 64 + lane];
  float mean = wave_sum64(a) * (1.f / 64.f);
  float d = a - mean;
  float var = wave_sum64(d * d) * (1.f / 64.f);
  float r = fmaxf(d * rsqrtf(var + 1e-5f) * flng[lane] + flnb[lane], 0.f);
  r1s[lane] = r;
  __syncthreads();
  if (lane < 32) {
    float a2 = fb2[lane];
    for (int k = 0; k < 64; ++k) a2 += r1s[k] * fw2[k * 32 + lane];
    r2s[lane] = fmaxf(a2, 0.f);
  }
  __syncthreads();
  if (lane < 16) {
    float a3 = pb1[lane];
    for (int k = 0; k < 32; ++k) a3 += r2s[k] * pw1[k * 16 + lane];
    r3s[lane] = fmaxf(a3, 0.f);
  }
  __syncthreads();
  if (lane == 0) {
    float a4 = pb2[0];
    for (int k = 0; k < 16; ++k) a4 += r3s[k] * pw2[k];
    out[g] = a4;
  }
}

// ---------- launch ----------

extern "C" void kernel_launch(void* const* d_in, const int* in_sizes, int n_in,
                              void* d_out, int out_size, void* d_ws, size_t ws_size,
                              hipStream_t stream) {
  const float* x = (const float*)d_in[0];
  const float* gf = (const float*)d_in[1];
  const int* ei = (const int*)d_in[2];
  const int* batch = (const int*)d_in[3];
  const float* in_w = (const float*)d_in[4];
  const float* in_b = (const float*)d_in[5];
  const float* in_ln_g = (const float*)d_in[6];
  const float* in_ln_b = (const float*)d_in[7];
  const float* gin_eps = (const float*)d_in[8];
  const float* gin_w1 = (const float*)d_in[9];
  const float* gin_b1 = (const float*)d_in[10];
  const float* gin_bn_g = (const float*)d_in[11];
  const float* gin_bn_b = (const float*)d_in[12];
  const float* gin_bn_m = (const float*)d_in[13];
  const float* gin_bn_v = (const float*)d_in[14];
  const float* gin_w2 = (const float*)d_in[15];
  const float* gin_b2 = (const float*)d_in[16];
  const float* gin_ln_g = (const float*)d_in[17];
  const float* gin_ln_b = (const float*)d_in[18];
  const float* gat_w = (const float*)d_in[19];
  const float* gat_asrc = (const float*)d_in[20];
  const float* gat_adst = (const float*)d_in[21];
  const float* gat_bias = (const float*)d_in[22];
  const float* gat_ln_g = (const float*)d_in[23];
  const float* gat_ln_b = (const float*)d_in[24];
  const float* fus_w1 = (const float*)d_in[25];
  const float* fus_b1 = (const float*)d_in[26];
  const float* fus_ln_g = (const float*)d_in[27];
  const float* fus_ln_b = (const float*)d_in[28];
  const float* fus_w2 = (const float*)d_in[29];
  const float* fus_b2 = (const float*)d_in[30];
  const float* pred_w1 = (const float*)d_in[31];
  const float* pred_b1 = (const float*)d_in[32];
  const float* pred_w2 = (const float*)d_in[33];
  const float* pred_b2 = (const float*)d_in[34];
  float* out = (float*)d_out;

  const int* src = ei;
  const int* dst = ei + N_EDGES;

  char* w = (char*)d_ws;
  float* hA = (float*)w;       w += (size_t)N_NODES * HID * 4;
  float* hB = (float*)w;       w += (size_t)N_NODES * HID * 4;   // GIN ping-pong; GAT xp
  float* asr = (float*)w;      w += (size_t)N_NODES * HEADS * 4;
  float* adt = (float*)w;      w += (size_t)N_NODES * HEADS * 4;
  int* deg = (int*)w;          w += (size_t)N_NODES * 4;
  int* ptr = (int*)w;          w += (size_t)N_NODES * 4;
  int* cur = (int*)w;          w += (size_t)N_NODES * 4;
  int* csr_src = (int*)w;      w += (size_t)N_EDGES * 4;
  int* bsum = (int*)w;         w += 512 * 4;
  int* boff = (int*)w;         w += 512 * 4;
  float* add_p = (float*)w;    w += (size_t)N_GRAPHS * HID * 4;
  float* sum_p = (float*)w;    w += (size_t)N_GRAPHS * HID * 4;
  unsigned* max_enc = (unsigned*)w; w += (size_t)N_GRAPHS * HID * 4;
  float* cnt = (float*)w;      w += (size_t)N_GRAPHS * 4;

  dim3 blk(256);
  int nwb = (N_NODES + 3) / 4;            // node-wave blocks (4 waves/block)
  int eb = (N_EDGES + 255) / 256;         // edge-thread blocks
  int nb256 = (N_NODES + 255) / 256;

  // --- CSR build (dst-bucketed) ---
  k_zero_int<<<nb256, blk, 0, stream>>>(deg, N_NODES);
  k_hist<<<eb, blk, 0, stream>>>(dst, deg);
  k_blocksum<<<NB_SCAN, blk, 0, stream>>>(deg, bsum);
  k_scanb<<<1, 512, 0, stream>>>(bsum, boff);
  k_offsets<<<NB_SCAN, blk, 0, stream>>>(deg, boff, ptr, cur);
  k_scatter<<<eb, blk, 0, stream>>>(src, dst, cur, csr_src);

  k_pool_init<<<(N_GRAPHS * HID + 255) / 256, blk, 0, stream>>>(add_p, sum_p, max_enc, cnt);
  k_input<<<nwb, blk, 0, stream>>>(x, gf, batch, in_w, in_b, in_ln_g, in_ln_b, hA);

  // --- GIN stack (ping-pong hA -> hB -> hA) ---
  for (int i = 0; i < 2; ++i) {
    const float* hin = (i == 0) ? hA : hB;
    float* hout = (i == 0) ? hB : hA;
    k_gin_fused<<<nwb, blk, 0, stream>>>(ptr, deg, csr_src, hin, hout, gin_eps + i,
        gin_w1 + (size_t)i * 64 * 128, gin_b1 + i * 128,
        gin_bn_g + i * 128, gin_bn_b + i * 128, gin_bn_m + i * 128, gin_bn_v + i * 128,
        gin_w2 + (size_t)i * 128 * 64, gin_b2 + i * 64,
        gin_ln_g + i * 64, gin_ln_b + i * 64,
        (i == 1) ? 1 : 0, batch, add_p, cnt);
  }

  // --- GAT stack (in place on hA; hB reused as xp) ---
  for (int i = 0; i < 2; ++i) {
    k_gat_pre<<<nwb, blk, 0, stream>>>(hA, gat_w + (size_t)i * 64 * 64,
        gat_asrc + i * HEADS * HEAD_DIM, gat_adst + i * HEADS * HEAD_DIM,
        hB, asr, adt);
    k_gat_agg<<<nwb, blk, 0, stream>>>(ptr, deg, csr_src, hB, asr, adt,
        gat_bias + i * 64, gat_ln_g + i * 64, gat_ln_b + i * 64, hA,
        (i == 1) ? 1 : 0, batch, sum_p, max_enc);
  }

  k_final<<<N_GRAPHS, 64, 0, stream>>>(add_p, sum_p, max_enc, cnt,
      fus_w1, fus_b1, fus_ln_g, fus_ln_b, fus_w2, fus_b2,
      pred_w1, pred_b1, pred_w2, pred_b2, out);
}

// Round 4
// 1259.962 us; speedup vs baseline: 1.9109x; 1.0392x over previous
//
#include <hip/hip_runtime.h>
#include <math.h>

#define N_NODES 100000
#define N_EDGES 1200000
#define N_GRAPHS 512
#define HID 64
#define HEADS 4
#define HEAD_DIM 16
#define IN_DIM 24
#define GDIM 10
#define NB_SCAN 391   // ceil(N_NODES/256)
#define NBLK 1563     // ceil(N_NODES/64)

// ---------- helpers ----------

__device__ __forceinline__ float wave_sum64(float v) {
#pragma unroll
  for (int m = 32; m >= 1; m >>= 1) v += __shfl_xor(v, m, 64);
  return v;
}

__device__ __forceinline__ unsigned enc_f(float f) {
  unsigned u = __float_as_uint(f);
  return (u & 0x80000000u) ? ~u : (u | 0x80000000u);
}
__device__ __forceinline__ float dec_f(unsigned u) {
  unsigned v = (u & 0x80000000u) ? (u & 0x7FFFFFFFu) : ~u;
  return __uint_as_float(v);
}

__device__ __forceinline__ float lrelu02(float x) {
  return x > 0.f ? x : 0.2f * x;
}

// ---------- CSR build ----------

__global__ void k_zero_int(int* __restrict__ p, int n) {
  int i = blockIdx.x * blockDim.x + threadIdx.x;
  if (i < n) p[i] = 0;
}

__global__ void k_hist(const int* __restrict__ dst, int* __restrict__ deg) {
  int e = blockIdx.x * blockDim.x + threadIdx.x;
  if (e < N_EDGES) atomicAdd(&deg[dst[e]], 1);
}

__global__ void k_blocksum(const int* __restrict__ deg, int* __restrict__ bsum) {
  __shared__ int s[256];
  int i = blockIdx.x * 256 + threadIdx.x;
  s[threadIdx.x] = (i < N_NODES) ? deg[i] : 0;
  __syncthreads();
  for (int off = 128; off >= 1; off >>= 1) {
    if (threadIdx.x < off) s[threadIdx.x] += s[threadIdx.x + off];
    __syncthreads();
  }
  if (threadIdx.x == 0) bsum[blockIdx.x] = s[0];
}

__global__ void k_scanb(const int* __restrict__ bsum, int* __restrict__ boff) {
  __shared__ int s[512];
  int tid = threadIdx.x;
  int v = (tid < NB_SCAN) ? bsum[tid] : 0;
  s[tid] = v;
  __syncthreads();
  for (int off = 1; off < 512; off <<= 1) {
    int t = (tid >= off) ? s[tid - off] : 0;
    __syncthreads();
    s[tid] += t;
    __syncthreads();
  }
  if (tid < NB_SCAN) boff[tid] = s[tid] - v;  // exclusive
}

__global__ void k_offsets(const int* __restrict__ deg, const int* __restrict__ boff,
                          int* __restrict__ ptr, int* __restrict__ cur) {
  __shared__ int s[256];
  int i = blockIdx.x * 256 + threadIdx.x;
  int v = (i < N_NODES) ? deg[i] : 0;
  s[threadIdx.x] = v;
  __syncthreads();
  for (int off = 1; off < 256; off <<= 1) {
    int t = (threadIdx.x >= off) ? s[threadIdx.x - off] : 0;
    __syncthreads();
    s[threadIdx.x] += t;
    __syncthreads();
  }
  if (i < N_NODES) {
    int p = boff[blockIdx.x] + s[threadIdx.x] - v;
    ptr[i] = p;
    cur[i] = p;
  }
}

__global__ void k_scatter(const int* __restrict__ src, const int* __restrict__ dst,
                          int* __restrict__ cur, int* __restrict__ csr_src) {
  int e = blockIdx.x * blockDim.x + threadIdx.x;
  if (e < N_EDGES) {
    int pos = atomicAdd(&cur[dst[e]], 1);
    csr_src[pos] = src[e];
  }
}

// transpose gin_w1 [L][64][128] -> w1t [L][128][64]
__global__ void k_prep_w1t(const float* __restrict__ gin_w1, float* __restrict__ w1t) {
  int i = blockIdx.x * 256 + threadIdx.x;
  if (i < 2 * 128 * 64) {
    int l = i >> 13, r = i & 8191, j = r >> 6, k = r & 63;
    w1t[i] = gin_w1[l * 8192 + k * 128 + j];
  }
}

// ---------- graph NN kernels ----------

__global__ void k_pool_init(float* __restrict__ add_p, float* __restrict__ sum_p,
                            unsigned* __restrict__ max_enc, float* __restrict__ cnt) {
  int i = blockIdx.x * blockDim.x + threadIdx.x;
  if (i < N_GRAPHS * HID) {
    add_p[i] = 0.f;
    sum_p[i] = 0.f;
    max_enc[i] = enc_f(-INFINITY);
  }
  if (i < N_GRAPHS) cnt[i] = 0.f;
}

// input projection + LN + relu. lane = node, SGPR weight rows, LDS transpose out.
__global__ __launch_bounds__(64) void k_input2(
    const float* __restrict__ x, const float* __restrict__ gf,
    const int* __restrict__ batch,
    const float* __restrict__ w, const float* __restrict__ b,
    const float* __restrict__ lng, const float* __restrict__ lnb,
    float* __restrict__ h) {
  __shared__ float lds[64 * 65];
  int lane = threadIdx.x;
  int nbase = blockIdx.x * 64;
  int node = nbase + lane;
  int nc = node < N_NODES ? node : N_NODES - 1;
  const float* xr = x + (size_t)nc * IN_DIM;
  int g = batch[nc];
  const float* gr = gf + (size_t)g * GDIM;
  float acc[64];
#pragma unroll
  for (int o = 0; o < 64; ++o) acc[o] = b[o];
  for (int kb = 0; kb < IN_DIM; kb += 4) {
    float f0 = xr[kb], f1 = xr[kb + 1], f2 = xr[kb + 2], f3 = xr[kb + 3];
    const float* w0 = w + (size_t)kb * 64;
#pragma unroll
    for (int o = 0; o < 64; ++o)
      acc[o] += f0 * w0[o] + f1 * w0[64 + o] + f2 * w0[128 + o] + f3 * w0[192 + o];
  }
  for (int kb = 0; kb < 8; kb += 4) {
    float f0 = gr[kb], f1 = gr[kb + 1], f2 = gr[kb + 2], f3 = gr[kb + 3];
    const float* w0 = w + (size_t)(IN_DIM + kb) * 64;
#pragma unroll
    for (int o = 0; o < 64; ++o)
      acc[o] += f0 * w0[o] + f1 * w0[64 + o] + f2 * w0[128 + o] + f3 * w0[192 + o];
  }
  {
    float f0 = gr[8], f1 = gr[9];
    const float* w0 = w + (size_t)(IN_DIM + 8) * 64;
#pragma unroll
    for (int o = 0; o < 64; ++o) acc[o] += f0 * w0[o] + f1 * w0[64 + o];
  }
  float s = 0.f;
#pragma unroll
  for (int o = 0; o < 64; ++o) s += acc[o];
  float mean = s * (1.f / 64.f);
  float s2 = 0.f;
#pragma unroll
  for (int o = 0; o < 64; ++o) { float d = acc[o] - mean; s2 += d * d; }
  float rs = rsqrtf(s2 * (1.f / 64.f) + 1e-5f);
#pragma unroll
  for (int o = 0; o < 64; ++o)
    lds[lane * 65 + o] = fmaxf((acc[o] - mean) * rs * lng[o] + lnb[o], 0.f);
  __syncthreads();
#pragma unroll 8
  for (int nd = 0; nd < 64; ++nd) {
    int n2 = nbase + nd;
    if (n2 >= N_NODES) break;
    h[(size_t)n2 * HID + lane] = lds[nd * 65 + lane];
  }
}

// GIN gather: wave per node, z = (1+eps)*h + sum_{in-edges} h[src]. Writes z rows.
__global__ void k_gin_gather(const int* __restrict__ ptr, const int* __restrict__ deg,
                             const int* __restrict__ csr_src,
                             const float* __restrict__ h_in, float* __restrict__ z,
                             const float* __restrict__ eps_p) {
  int n = (blockIdx.x * blockDim.x + threadIdx.x) >> 6;
  int lane = threadIdx.x & 63;
  if (n >= N_NODES) return;
  int base = ptr[n], dg = deg[n];
  float hj = h_in[(size_t)n * HID + lane];
  float agg = 0.f;
  for (int c = 0; c < dg; c += 64) {
    int rem = dg - c; if (rem > 64) rem = 64;
    int idx = (lane < rem) ? csr_src[base + c + lane] : 0;
    int it = 0;
    for (; it + 8 <= rem; it += 8) {
      int s0 = __shfl(idx, it, 64);
      int s1 = __shfl(idx, it + 1, 64);
      int s2 = __shfl(idx, it + 2, 64);
      int s3 = __shfl(idx, it + 3, 64);
      int s4 = __shfl(idx, it + 4, 64);
      int s5 = __shfl(idx, it + 5, 64);
      int s6 = __shfl(idx, it + 6, 64);
      int s7 = __shfl(idx, it + 7, 64);
      float v0 = h_in[(size_t)s0 * HID + lane];
      float v1 = h_in[(size_t)s1 * HID + lane];
      float v2 = h_in[(size_t)s2 * HID + lane];
      float v3 = h_in[(size_t)s3 * HID + lane];
      float v4 = h_in[(size_t)s4 * HID + lane];
      float v5 = h_in[(size_t)s5 * HID + lane];
      float v6 = h_in[(size_t)s6 * HID + lane];
      float v7 = h_in[(size_t)s7 * HID + lane];
      agg += ((v0 + v1) + (v2 + v3)) + ((v4 + v5) + (v6 + v7));
    }
    for (; it + 4 <= rem; it += 4) {
      int s0 = __shfl(idx, it, 64);
      int s1 = __shfl(idx, it + 1, 64);
      int s2 = __shfl(idx, it + 2, 64);
      int s3 = __shfl(idx, it + 3, 64);
      float v0 = h_in[(size_t)s0 * HID + lane];
      float v1 = h_in[(size_t)s1 * HID + lane];
      float v2 = h_in[(size_t)s2 * HID + lane];
      float v3 = h_in[(size_t)s3 * HID + lane];
      agg += (v0 + v1) + (v2 + v3);
    }
    for (; it < rem; ++it) {
      int s = __shfl(idx, it, 64);
      agg += h_in[(size_t)s * HID + lane];
    }
  }
  z[(size_t)n * HID + lane] = (1.f + eps_p[0]) * hj + agg;
}

// GIN MLP: lane = node. z row in regs; weights via uniform (SGPR) loads.
// MLP1(64->128)+BN+relu, MLP2(128->64)+b2, LN in-lane, relu, +residual via
// LDS-transposed coalesced writes. Optional add-pool epilogue.
__global__ __launch_bounds__(64) void k_gin_mlp(
    const float* __restrict__ z, const float* __restrict__ h_in,
    float* __restrict__ h_out,
    const float* __restrict__ w1t, const float* __restrict__ b1,
    const float* __restrict__ bng, const float* __restrict__ bnb,
    const float* __restrict__ bnm, const float* __restrict__ bnv,
    const float* __restrict__ w2, const float* __restrict__ b2,
    const float* __restrict__ lng, const float* __restrict__ lnb,
    int do_pool, const int* __restrict__ batch,
    float* __restrict__ add_p, float* __restrict__ cnt) {
  __shared__ float lds[64 * 65];
  int lane = threadIdx.x;
  int nbase = blockIdx.x * 64;
  int node = nbase + lane;
  int nc = node < N_NODES ? node : N_NODES - 1;
  const float4* zr = (const float4*)(z + (size_t)nc * HID);
  float z_[64];
#pragma unroll
  for (int t = 0; t < 16; ++t) {
    float4 q = zr[t];
    z_[4 * t] = q.x; z_[4 * t + 1] = q.y; z_[4 * t + 2] = q.z; z_[4 * t + 3] = q.w;
  }
  float o_[64];
#pragma unroll
  for (int t = 0; t < 64; ++t) o_[t] = 0.f;
  for (int j = 0; j < 128; ++j) {
    const float* wr = w1t + (size_t)j * 64;
    float a0 = 0.f, a1 = 0.f, a2 = 0.f, a3 = 0.f;
#pragma unroll
    for (int k = 0; k < 64; k += 4) {
      a0 += z_[k] * wr[k];
      a1 += z_[k + 1] * wr[k + 1];
      a2 += z_[k + 2] * wr[k + 2];
      a3 += z_[k + 3] * wr[k + 3];
    }
    float aj = (a0 + a1) + (a2 + a3) + b1[j];
    aj = (aj - bnm[j]) * rsqrtf(bnv[j] + 1e-5f) * bng[j] + bnb[j];
    float r = fmaxf(aj, 0.f);
    const float* w2r = w2 + (size_t)j * 64;
#pragma unroll
    for (int t = 0; t < 64; ++t) o_[t] += r * w2r[t];
  }
#pragma unroll
  for (int t = 0; t < 64; ++t) o_[t] += b2[t];
  float s = 0.f;
#pragma unroll
  for (int t = 0; t < 64; ++t) s += o_[t];
  float mean = s * (1.f / 64.f);
  float s2 = 0.f;
#pragma unroll
  for (int t = 0; t < 64; ++t) { float d = o_[t] - mean; s2 += d * d; }
  float rs = rsqrtf(s2 * (1.f / 64.f) + 1e-5f);
#pragma unroll
  for (int t = 0; t < 64; ++t)
    lds[lane * 65 + t] = fmaxf((o_[t] - mean) * rs * lng[t] + lnb[t], 0.f);
  __syncthreads();
#pragma unroll 8
  for (int nd = 0; nd < 64; ++nd) {
    int n2 = nbase + nd;
    if (n2 >= N_NODES) break;
    float val = lds[nd * 65 + lane] + h_in[(size_t)n2 * HID + lane];
    h_out[(size_t)n2 * HID + lane] = val;
    if (do_pool) {
      int g = batch[n2];
      atomicAdd(&add_p[g * HID + lane], val);
      if (lane == 0) atomicAdd(&cnt[g], 1.f);
    }
  }
}

// GAT precompute: lane = node. xp = h @ W (SGPR weight rows), head dots in-lane.
__global__ __launch_bounds__(64) void k_gat_pre2(
    const float* __restrict__ h, const float* __restrict__ w,
    const float* __restrict__ asrc, const float* __restrict__ adst,
    float* __restrict__ xp, float* __restrict__ asr, float* __restrict__ adt) {
  __shared__ float lds[64 * 65];
  int lane = threadIdx.x;
  int nbase = blockIdx.x * 64;
  int node = nbase + lane;
  int nc = node < N_NODES ? node : N_NODES - 1;
  const float4* hr = (const float4*)(h + (size_t)nc * HID);
  float p_[64];
#pragma unroll
  for (int o = 0; o < 64; ++o) p_[o] = 0.f;
  for (int kc = 0; kc < 16; ++kc) {
    float4 q = hr[kc];
    const float* w0 = w + (size_t)(kc * 4) * 64;
#pragma unroll
    for (int o = 0; o < 64; ++o)
      p_[o] += q.x * w0[o] + q.y * w0[64 + o] + q.z * w0[128 + o] + q.w * w0[192 + o];
  }
  float as[4], ad[4];
#pragma unroll
  for (int hh = 0; hh < 4; ++hh) {
    float sa = 0.f, sd = 0.f;
#pragma unroll
    for (int d = 0; d < 16; ++d) {
      sa += p_[hh * 16 + d] * asrc[hh * 16 + d];
      sd += p_[hh * 16 + d] * adst[hh * 16 + d];
    }
    as[hh] = sa; ad[hh] = sd;
  }
  if (node < N_NODES) {
    float4 va; va.x = as[0]; va.y = as[1]; va.z = as[2]; va.w = as[3];
    float4 vd; vd.x = ad[0]; vd.y = ad[1]; vd.z = ad[2]; vd.w = ad[3];
    *(float4*)(asr + (size_t)node * 4) = va;
    *(float4*)(adt + (size_t)node * 4) = vd;
  }
#pragma unroll
  for (int o = 0; o < 64; ++o) lds[lane * 65 + o] = p_[o];
  __syncthreads();
#pragma unroll 8
  for (int nd = 0; nd < 64; ++nd) {
    int n2 = nbase + nd;
    if (n2 >= N_NODES) break;
    xp[(size_t)n2 * HID + lane] = lds[nd * 65 + lane];
  }
}

// Fused GAT aggregation (wave per node, lane = feature). Unchanged from R3.
__global__ void k_gat_agg(const int* __restrict__ ptr, const int* __restrict__ deg,
                          const int* __restrict__ csr_src,
                          const float* __restrict__ xp, const float* __restrict__ asr,
                          const float* __restrict__ adt,
                          const float* __restrict__ bias,
                          const float* __restrict__ lng, const float* __restrict__ lnb,
                          float* __restrict__ h,
                          int do_pool, const int* __restrict__ batch,
                          float* __restrict__ sum_p, unsigned* __restrict__ max_enc) {
  int n = (blockIdx.x * blockDim.x + threadIdx.x) >> 6;
  int lane = threadIdx.x & 63;
  if (n >= N_NODES) return;
  int head = lane >> 4, sub = lane & 15;
  int base = ptr[n], dg = deg[n];
  float adt_d = adt[n * HEADS + head];
  float el = lrelu02(asr[n * HEADS + head] + adt_d);
  int rem0 = dg < 64 ? dg : 64;
  int idx0 = (lane < rem0) ? csr_src[base + lane] : 0;
  float pm = -1e30f, ps = 0.f;
  for (int c = 0; c < dg; c += 64) {
    int rem = dg - c; if (rem > 64) rem = 64;
    int idx = (c == 0) ? idx0 : ((lane < rem) ? csr_src[base + c + lane] : 0);
    for (int j = sub; j < rem; j += 16) {
      int s = __shfl(idx, j, 64);
      float e = lrelu02(asr[s * HEADS + head] + adt_d);
      float nm = fmaxf(pm, e);
      ps = ps * __expf(pm - nm) + __expf(e - nm);
      pm = nm;
    }
  }
#pragma unroll
  for (int msk = 1; msk <= 8; msk <<= 1) {
    float om = __shfl_xor(pm, msk, 64);
    float os = __shfl_xor(ps, msk, 64);
    float nm = fmaxf(pm, om);
    ps = ps * __expf(pm - nm) + os * __expf(om - nm);
    pm = nm;
  }
  float mfin = fmaxf(pm, el);
  float psum = ps * __expf(pm - mfin) + __expf(el - mfin);
  float o = __expf(el - mfin) * xp[(size_t)n * HID + lane];
  for (int c = 0; c < dg; c += 64) {
    int rem = dg - c; if (rem > 64) rem = 64;
    int idx = (c == 0) ? idx0 : ((lane < rem) ? csr_src[base + c + lane] : 0);
    int it = 0;
    for (; it + 4 <= rem; it += 4) {
      int s0 = __shfl(idx, it, 64);
      int s1 = __shfl(idx, it + 1, 64);
      int s2 = __shfl(idx, it + 2, 64);
      int s3 = __shfl(idx, it + 3, 64);
      float q0 = asr[s0 * HEADS + head];
      float q1 = asr[s1 * HEADS + head];
      float q2 = asr[s2 * HEADS + head];
      float q3 = asr[s3 * HEADS + head];
      float x0 = xp[(size_t)s0 * HID + lane];
      float x1 = xp[(size_t)s1 * HID + lane];
      float x2 = xp[(size_t)s2 * HID + lane];
      float x3 = xp[(size_t)s3 * HID + lane];
      float p0 = __expf(lrelu02(q0 + adt_d) - mfin);
      float p1 = __expf(lrelu02(q1 + adt_d) - mfin);
      float p2 = __expf(lrelu02(q2 + adt_d) - mfin);
      float p3 = __expf(lrelu02(q3 + adt_d) - mfin);
      o += (p0 * x0 + p1 * x1) + (p2 * x2 + p3 * x3);
    }
    for (; it < rem; ++it) {
      int s = __shfl(idx, it, 64);
      float e = lrelu02(asr[s * HEADS + head] + adt_d);
      o += __expf(e - mfin) * xp[(size_t)s * HID + lane];
    }
  }
  o = o / psum + bias[lane];
  float mean = wave_sum64(o) * (1.f / 64.f);
  float d = o - mean;
  float var = wave_sum64(d * d) * (1.f / 64.f);
  float v = d * rsqrtf(var + 1e-5f) * lng[lane] + lnb[lane];
  float e2 = v > 0.f ? v : expm1f(v);
  float hnew = e2 + h[(size_t)n * HID + lane];
  h[(size_t)n * HID + lane] = hnew;
  if (do_pool) {
    int g = batch[n];
    atomicAdd(&sum_p[g * HID + lane], hnew);
    atomicMax(&max_enc[g * HID + lane], enc_f(hnew));
  }
}

// final per-graph MLP. one wave per graph.
__global__ void k_final(const float* __restrict__ add_p, const float* __restrict__ sum_p,
                        const unsigned* __restrict__ max_enc, const float* __restrict__ cnt,
                        const float* __restrict__ fw1, const float* __restrict__ fb1,
                        const float* __restrict__ flng, const float* __restrict__ flnb,
                        const float* __restrict__ fw2, const float* __restrict__ fb2,
                        const float* __restrict__ pw1, const float* __restrict__ pb1,
                        const float* __restrict__ pw2, const float* __restrict__ pb2,
                        float* __restrict__ out) {
  __shared__ float buf[192];
  __shared__ float r1s[64];
  __shared__ float r2s[32];
  __shared__ float r3s[16];
  int g = blockIdx.x;
  int lane = threadIdx.x;
  float c = fmaxf(cnt[g], 1.f);
  buf[lane] = add_p[g * HID + lane];
  buf[64 + lane] = sum_p[g * HID + lane] / c;
  float mx = dec_f(max_enc[g * HID + lane]);
  if (!isfinite(mx)) mx = 0.f;
  buf[128 + lane] = mx;
  __syncthreads();
  float a = fb1[lane];
  for (int k = 0; k < 192; ++k) a += buf[k] * fw1[k * 64 + lane];
  float mean = wave_sum64(a) * (1.f / 64.f);
  float d = a - mean;
  float var = wave_sum64(d * d) * (1.f / 64.f);
  float r = fmaxf(d * rsqrtf(var + 1e-5f) * flng[lane] + flnb[lane], 0.f);
  r1s[lane] = r;
  __syncthreads();
  if (lane < 32) {
    float a2 = fb2[lane];
    for (int k = 0; k < 64; ++k) a2 += r1s[k] * fw2[k * 32 + lane];
    r2s[lane] = fmaxf(a2, 0.f);
  }
  __syncthreads();
  if (lane < 16) {
    float a3 = pb1[lane];
    for (int k = 0; k < 32; ++k) a3 += r2s[k] * pw1[k * 16 + lane];
    r3s[lane] = fmaxf(a3, 0.f);
  }
  __syncthreads();
  if (lane == 0) {
    float a4 = pb2[0];
    for (int k = 0; k < 16; ++k) a4 += r3s[k] * pw2[k];
    out[g] = a4;
  }
}

// ---------- launch ----------

extern "C" void kernel_launch(void* const* d_in, const int* in_sizes, int n_in,
                              void* d_out, int out_size, void* d_ws, size_t ws_size,
                              hipStream_t stream) {
  const float* x = (const float*)d_in[0];
  const float* gf = (const float*)d_in[1];
  const int* ei = (const int*)d_in[2];
  const int* batch = (const int*)d_in[3];
  const float* in_w = (const float*)d_in[4];
  const float* in_b = (const float*)d_in[5];
  const float* in_ln_g = (const float*)d_in[6];
  const float* in_ln_b = (const float*)d_in[7];
  const float* gin_eps = (const float*)d_in[8];
  const float* gin_w1 = (const float*)d_in[9];
  const float* gin_b1 = (const float*)d_in[10];
  const float* gin_bn_g = (const float*)d_in[11];
  const float* gin_bn_b = (const float*)d_in[12];
  const float* gin_bn_m = (const float*)d_in[13];
  const float* gin_bn_v = (const float*)d_in[14];
  const float* gin_w2 = (const float*)d_in[15];
  const float* gin_b2 = (const float*)d_in[16];
  const float* gin_ln_g = (const float*)d_in[17];
  const float* gin_ln_b = (const float*)d_in[18];
  const float* gat_w = (const float*)d_in[19];
  const float* gat_asrc = (const float*)d_in[20];
  const float* gat_adst = (const float*)d_in[21];
  const float* gat_bias = (const float*)d_in[22];
  const float* gat_ln_g = (const float*)d_in[23];
  const float* gat_ln_b = (const float*)d_in[24];
  const float* fus_w1 = (const float*)d_in[25];
  const float* fus_b1 = (const float*)d_in[26];
  const float* fus_ln_g = (const float*)d_in[27];
  const float* fus_ln_b = (const float*)d_in[28];
  const float* fus_w2 = (const float*)d_in[29];
  const float* fus_b2 = (const float*)d_in[30];
  const float* pred_w1 = (const float*)d_in[31];
  const float* pred_b1 = (const float*)d_in[32];
  const float* pred_w2 = (const float*)d_in[33];
  const float* pred_b2 = (const float*)d_in[34];
  float* out = (float*)d_out;

  const int* src = ei;
  const int* dst = ei + N_EDGES;

  char* w = (char*)d_ws;
  float* hA = (float*)w;       w += (size_t)N_NODES * HID * 4;
  float* hB = (float*)w;       w += (size_t)N_NODES * HID * 4;   // GIN ping-pong; GAT xp
  float* zbuf = (float*)w;     w += (size_t)N_NODES * HID * 4;
  float* asr = (float*)w;      w += (size_t)N_NODES * HEADS * 4;
  float* adt = (float*)w;      w += (size_t)N_NODES * HEADS * 4;
  int* deg = (int*)w;          w += (size_t)N_NODES * 4;
  int* ptr = (int*)w;          w += (size_t)N_NODES * 4;
  int* cur = (int*)w;          w += (size_t)N_NODES * 4;
  int* csr_src = (int*)w;      w += (size_t)N_EDGES * 4;
  int* bsum = (int*)w;         w += 512 * 4;
  int* boff = (int*)w;         w += 512 * 4;
  float* w1t = (float*)w;      w += (size_t)2 * 128 * 64 * 4;
  float* add_p = (float*)w;    w += (size_t)N_GRAPHS * HID * 4;
  float* sum_p = (float*)w;    w += (size_t)N_GRAPHS * HID * 4;
  unsigned* max_enc = (unsigned*)w; w += (size_t)N_GRAPHS * HID * 4;
  float* cnt = (float*)w;      w += (size_t)N_GRAPHS * 4;

  dim3 blk(256);
  int nwb = (N_NODES + 3) / 4;            // node-wave blocks (4 waves/block)
  int eb = (N_EDGES + 255) / 256;
  int nb256 = (N_NODES + 255) / 256;

  // --- prep: CSR build + w1 transpose ---
  k_zero_int<<<nb256, blk, 0, stream>>>(deg, N_NODES);
  k_hist<<<eb, blk, 0, stream>>>(dst, deg);
  k_blocksum<<<NB_SCAN, blk, 0, stream>>>(deg, bsum);
  k_scanb<<<1, 512, 0, stream>>>(bsum, boff);
  k_offsets<<<NB_SCAN, blk, 0, stream>>>(deg, boff, ptr, cur);
  k_scatter<<<eb, blk, 0, stream>>>(src, dst, cur, csr_src);
  k_prep_w1t<<<64, blk, 0, stream>>>(gin_w1, w1t);

  k_pool_init<<<(N_GRAPHS * HID + 255) / 256, blk, 0, stream>>>(add_p, sum_p, max_enc, cnt);
  k_input2<<<NBLK, 64, 0, stream>>>(x, gf, batch, in_w, in_b, in_ln_g, in_ln_b, hA);

  // --- GIN stack (ping-pong hA -> hB -> hA) ---
  for (int i = 0; i < 2; ++i) {
    const float* hin = (i == 0) ? hA : hB;
    float* hout = (i == 0) ? hB : hA;
    k_gin_gather<<<nwb, blk, 0, stream>>>(ptr, deg, csr_src, hin, zbuf, gin_eps + i);
    k_gin_mlp<<<NBLK, 64, 0, stream>>>(zbuf, hin, hout,
        w1t + (size_t)i * 128 * 64, gin_b1 + i * 128,
        gin_bn_g + i * 128, gin_bn_b + i * 128, gin_bn_m + i * 128, gin_bn_v + i * 128,
        gin_w2 + (size_t)i * 128 * 64, gin_b2 + i * 64,
        gin_ln_g + i * 64, gin_ln_b + i * 64,
        (i == 1) ? 1 : 0, batch, add_p, cnt);
  }

  // --- GAT stack (in place on hA; hB reused as xp) ---
  for (int i = 0; i < 2; ++i) {
    k_gat_pre2<<<NBLK, 64, 0, stream>>>(hA, gat_w + (size_t)i * 64 * 64,
        gat_asrc + i * HEADS * HEAD_DIM, gat_adst + i * HEADS * HEAD_DIM,
        hB, asr, adt);
    k_gat_agg<<<nwb, blk, 0, stream>>>(ptr, deg, csr_src, hB, asr, adt,
        gat_bias + i * 64, gat_ln_g + i * 64, gat_ln_b + i * 64, hA,
        (i == 1) ? 1 : 0, batch, sum_p, max_enc);
  }

  k_final<<<N_GRAPHS, 64, 0, stream>>>(add_p, sum_p, max_enc, cnt,
      fus_w1, fus_b1, fus_ln_g, fus_ln_b, fus_w2, fus_b2,
      pred_w1, pred_b1, pred_w2, pred_b2, out);
}

// Round 5
// 992.544 us; speedup vs baseline: 2.4258x; 1.2694x over previous
//
#include <hip/hip_runtime.h>
#include <math.h>

#define N_NODES 100000
#define N_EDGES 1200000
#define N_GRAPHS 512
#define HID 64
#define HEADS 4
#define HEAD_DIM 16
#define IN_DIM 24
#define GDIM 10
#define NB_SCAN 391   // ceil(N_NODES/256)
#define NBLK 1563     // ceil(N_NODES/64)

// ---------- helpers ----------

__device__ __forceinline__ float wave_sum64(float v) {
#pragma unroll
  for (int m = 32; m >= 1; m >>= 1) v += __shfl_xor(v, m, 64);
  return v;
}

__device__ __forceinline__ float head_sum16(float v) {
#pragma unroll
  for (int m = 8; m >= 1; m >>= 1) v += __shfl_xor(v, m, 64);
  return v;
}

__device__ __forceinline__ unsigned enc_f(float f) {
  unsigned u = __float_as_uint(f);
  return (u & 0x80000000u) ? ~u : (u | 0x80000000u);
}
__device__ __forceinline__ float dec_f(unsigned u) {
  unsigned v = (u & 0x80000000u) ? (u & 0x7FFFFFFFu) : ~u;
  return __uint_as_float(v);
}

__device__ __forceinline__ float lrelu02(float x) {
  return x > 0.f ? x : 0.2f * x;
}

// ---------- CSR build ----------

__global__ void k_zero_int(int* __restrict__ p, int n) {
  int i = blockIdx.x * blockDim.x + threadIdx.x;
  if (i < n) p[i] = 0;
}

__global__ void k_hist(const int* __restrict__ dst, int* __restrict__ deg) {
  int e = blockIdx.x * blockDim.x + threadIdx.x;
  if (e < N_EDGES) atomicAdd(&deg[dst[e]], 1);
}

__global__ void k_blocksum(const int* __restrict__ deg, int* __restrict__ bsum) {
  __shared__ int s[256];
  int i = blockIdx.x * 256 + threadIdx.x;
  s[threadIdx.x] = (i < N_NODES) ? deg[i] : 0;
  __syncthreads();
  for (int off = 128; off >= 1; off >>= 1) {
    if (threadIdx.x < off) s[threadIdx.x] += s[threadIdx.x + off];
    __syncthreads();
  }
  if (threadIdx.x == 0) bsum[blockIdx.x] = s[0];
}

__global__ void k_scanb(const int* __restrict__ bsum, int* __restrict__ boff) {
  __shared__ int s[512];
  int tid = threadIdx.x;
  int v = (tid < NB_SCAN) ? bsum[tid] : 0;
  s[tid] = v;
  __syncthreads();
  for (int off = 1; off < 512; off <<= 1) {
    int t = (tid >= off) ? s[tid - off] : 0;
    __syncthreads();
    s[tid] += t;
    __syncthreads();
  }
  if (tid < NB_SCAN) boff[tid] = s[tid] - v;  // exclusive
}

__global__ void k_offsets(const int* __restrict__ deg, const int* __restrict__ boff,
                          int* __restrict__ ptr, int* __restrict__ cur) {
  __shared__ int s[256];
  int i = blockIdx.x * 256 + threadIdx.x;
  int v = (i < N_NODES) ? deg[i] : 0;
  s[threadIdx.x] = v;
  __syncthreads();
  for (int off = 1; off < 256; off <<= 1) {
    int t = (threadIdx.x >= off) ? s[threadIdx.x - off] : 0;
    __syncthreads();
    s[threadIdx.x] += t;
    __syncthreads();
  }
  if (i < N_NODES) {
    int p = boff[blockIdx.x] + s[threadIdx.x] - v;
    ptr[i] = p;
    cur[i] = p;
  }
}

__global__ void k_scatter(const int* __restrict__ src, const int* __restrict__ dst,
                          int* __restrict__ cur, int* __restrict__ csr_src) {
  int e = blockIdx.x * blockDim.x + threadIdx.x;
  if (e < N_EDGES) {
    int pos = atomicAdd(&cur[dst[e]], 1);
    csr_src[pos] = src[e];
  }
}

// ---------- graph NN kernels ----------

__global__ void k_pool_init(float* __restrict__ add_p, float* __restrict__ sum_p,
                            unsigned* __restrict__ max_enc, float* __restrict__ cnt) {
  int i = blockIdx.x * blockDim.x + threadIdx.x;
  if (i < N_GRAPHS * HID) {
    add_p[i] = 0.f;
    sum_p[i] = 0.f;
    max_enc[i] = enc_f(-INFINITY);
  }
  if (i < N_GRAPHS) cnt[i] = 0.f;
}

// input projection + LN + relu. one wave per node, lane = feature.
__global__ void k_input(const float* __restrict__ x, const float* __restrict__ gf,
                        const int* __restrict__ batch,
                        const float* __restrict__ w, const float* __restrict__ b,
                        const float* __restrict__ lng, const float* __restrict__ lnb,
                        float* __restrict__ h) {
  int n = (blockIdx.x * blockDim.x + threadIdx.x) >> 6;
  int lane = threadIdx.x & 63;
  if (n >= N_NODES) return;
  int g = batch[n];
  float feat = 0.f;
  if (lane < IN_DIM) feat = x[n * IN_DIM + lane];
  else if (lane < IN_DIM + GDIM) feat = gf[g * GDIM + (lane - IN_DIM)];
  float acc = b[lane];
#pragma unroll
  for (int k = 0; k < IN_DIM + GDIM; ++k) {
    float fk = __shfl(feat, k, 64);
    acc += fk * w[k * HID + lane];
  }
  float mean = wave_sum64(acc) * (1.f / 64.f);
  float d = acc - mean;
  float var = wave_sum64(d * d) * (1.f / 64.f);
  float v = d * rsqrtf(var + 1e-5f) * lng[lane] + lnb[lane];
  h[n * HID + lane] = fmaxf(v, 0.f);
}

// GIN gather: wave per node, z = (1+eps)*h + sum_{in-edges} h[src]. Writes z rows.
__global__ void k_gin_gather(const int* __restrict__ ptr, const int* __restrict__ deg,
                             const int* __restrict__ csr_src,
                             const float* __restrict__ h_in, float* __restrict__ z,
                             const float* __restrict__ eps_p) {
  int n = (blockIdx.x * blockDim.x + threadIdx.x) >> 6;
  int lane = threadIdx.x & 63;
  if (n >= N_NODES) return;
  int base = ptr[n], dg = deg[n];
  float hj = h_in[(size_t)n * HID + lane];
  float agg = 0.f;
  for (int c = 0; c < dg; c += 64) {
    int rem = dg - c; if (rem > 64) rem = 64;
    int idx = (lane < rem) ? csr_src[base + c + lane] : 0;
    int it = 0;
    for (; it + 8 <= rem; it += 8) {
      int s0 = __shfl(idx, it, 64);
      int s1 = __shfl(idx, it + 1, 64);
      int s2 = __shfl(idx, it + 2, 64);
      int s3 = __shfl(idx, it + 3, 64);
      int s4 = __shfl(idx, it + 4, 64);
      int s5 = __shfl(idx, it + 5, 64);
      int s6 = __shfl(idx, it + 6, 64);
      int s7 = __shfl(idx, it + 7, 64);
      float v0 = h_in[(size_t)s0 * HID + lane];
      float v1 = h_in[(size_t)s1 * HID + lane];
      float v2 = h_in[(size_t)s2 * HID + lane];
      float v3 = h_in[(size_t)s3 * HID + lane];
      float v4 = h_in[(size_t)s4 * HID + lane];
      float v5 = h_in[(size_t)s5 * HID + lane];
      float v6 = h_in[(size_t)s6 * HID + lane];
      float v7 = h_in[(size_t)s7 * HID + lane];
      agg += ((v0 + v1) + (v2 + v3)) + ((v4 + v5) + (v6 + v7));
    }
    for (; it + 4 <= rem; it += 4) {
      int s0 = __shfl(idx, it, 64);
      int s1 = __shfl(idx, it + 1, 64);
      int s2 = __shfl(idx, it + 2, 64);
      int s3 = __shfl(idx, it + 3, 64);
      float v0 = h_in[(size_t)s0 * HID + lane];
      float v1 = h_in[(size_t)s1 * HID + lane];
      float v2 = h_in[(size_t)s2 * HID + lane];
      float v3 = h_in[(size_t)s3 * HID + lane];
      agg += (v0 + v1) + (v2 + v3);
    }
    for (; it < rem; ++it) {
      int s = __shfl(idx, it, 64);
      agg += h_in[(size_t)s * HID + lane];
    }
  }
  z[(size_t)n * HID + lane] = (1.f + eps_p[0]) * hj + agg;
}

// GIN MLP: LDS-tiled fp32 GEMM. Block = 256 threads (16 tx x 16 ty), 64-node tile.
// GEMM1 (64x128x64): thread tile 4 nodes x 8 outs. BN+relu in regs.
// GEMM2 (64x64x128): thread tile 4 nodes x 4 outs. LN via shfl over tx.
// LDS: phase A zT[64][68] + w1[64][128]; phase B rT(swizzled)[128][64] + w2[128][64].
#define ZT_S 68
__global__ __launch_bounds__(256) void k_gin_mlp2(
    const float* __restrict__ z, const float* __restrict__ h_in,
    float* __restrict__ h_out,
    const float* __restrict__ w1, const float* __restrict__ b1,
    const float* __restrict__ bng, const float* __restrict__ bnb,
    const float* __restrict__ bnm, const float* __restrict__ bnv,
    const float* __restrict__ w2, const float* __restrict__ b2,
    const float* __restrict__ lng, const float* __restrict__ lnb,
    int do_pool, const int* __restrict__ batch,
    float* __restrict__ add_p, float* __restrict__ cnt) {
  __shared__ float smem[16384];           // 64 KB exactly
  float* zT = smem;                       // [64][ZT_S]  (phase A)
  float* w1s = smem + 64 * ZT_S;          // [64][128]   (phase A)
  float* rT = smem;                       // [128][64] swizzled (phase B)
  float* w2s = smem + 8192;               // [128][64]   (phase B)
  int tid = threadIdx.x;
  int tx = tid & 15, ty = tid >> 4;
  int tx4 = tx * 4, tx8 = tx * 8, ty4 = ty * 4;
  int nbase = blockIdx.x * 64;
  // ---- stage zT (transposed) ----
#pragma unroll
  for (int r = 0; r < 4; ++r) {
    int e = r * 256 + tid;                // 0..1023 = 64 nodes * 16 float4
    int nd = e >> 4, kq = e & 15;
    int node = nbase + nd;
    int nc = node < N_NODES ? node : N_NODES - 1;
    float4 v = ((const float4*)(z + (size_t)nc * HID))[kq];
    zT[(kq * 4 + 0) * ZT_S + nd] = v.x;
    zT[(kq * 4 + 1) * ZT_S + nd] = v.y;
    zT[(kq * 4 + 2) * ZT_S + nd] = v.z;
    zT[(kq * 4 + 3) * ZT_S + nd] = v.w;
  }
  // ---- stage w1 (raw copy [64][128]) ----
#pragma unroll
  for (int r = 0; r < 8; ++r)
    ((float4*)w1s)[r * 256 + tid] = ((const float4*)w1)[r * 256 + tid];
  __syncthreads();
  // ---- GEMM1 ----
  float c1[4][8];
#pragma unroll
  for (int mm = 0; mm < 4; ++mm)
#pragma unroll
    for (int jj = 0; jj < 8; ++jj) c1[mm][jj] = 0.f;
  for (int k = 0; k < 64; ++k) {
    float4 a = *(const float4*)&zT[k * ZT_S + ty4];
    float4 b0 = *(const float4*)&w1s[k * 128 + tx8];
    float4 b1v = *(const float4*)&w1s[k * 128 + tx8 + 4];
    float av[4] = {a.x, a.y, a.z, a.w};
    float bv[8] = {b0.x, b0.y, b0.z, b0.w, b1v.x, b1v.y, b1v.z, b1v.w};
#pragma unroll
    for (int mm = 0; mm < 4; ++mm)
#pragma unroll
      for (int jj = 0; jj < 8; ++jj) c1[mm][jj] += av[mm] * bv[jj];
  }
  // ---- bias + BN + relu (per j = tx8+jj) ----
  {
    float4 bb0 = *(const float4*)&b1[tx8];
    float4 bb1 = *(const float4*)&b1[tx8 + 4];
    float4 m0 = *(const float4*)&bnm[tx8];
    float4 m1 = *(const float4*)&bnm[tx8 + 4];
    float4 v0 = *(const float4*)&bnv[tx8];
    float4 v1 = *(const float4*)&bnv[tx8 + 4];
    float4 g0 = *(const float4*)&bng[tx8];
    float4 g1 = *(const float4*)&bng[tx8 + 4];
    float4 q0 = *(const float4*)&bnb[tx8];
    float4 q1 = *(const float4*)&bnb[tx8 + 4];
    float bbv[8] = {bb0.x, bb0.y, bb0.z, bb0.w, bb1.x, bb1.y, bb1.z, bb1.w};
    float mv[8] = {m0.x, m0.y, m0.z, m0.w, m1.x, m1.y, m1.z, m1.w};
    float vv[8] = {v0.x, v0.y, v0.z, v0.w, v1.x, v1.y, v1.z, v1.w};
    float gv[8] = {g0.x, g0.y, g0.z, g0.w, g1.x, g1.y, g1.z, g1.w};
    float qv[8] = {q0.x, q0.y, q0.z, q0.w, q1.x, q1.y, q1.z, q1.w};
#pragma unroll
    for (int jj = 0; jj < 8; ++jj) {
      float sc = gv[jj] * rsqrtf(vv[jj] + 1e-5f);
      float sh = qv[jj] + (bbv[jj] - mv[jj]) * sc;
#pragma unroll
      for (int mm = 0; mm < 4; ++mm)
        c1[mm][jj] = fmaxf(c1[mm][jj] * sc + sh, 0.f);
    }
  }
  __syncthreads();   // everyone done with zT/w1s
  // ---- stage w2 + write swizzled rT ----
#pragma unroll
  for (int r = 0; r < 8; ++r)
    ((float4*)w2s)[r * 256 + tid] = ((const float4*)w2)[r * 256 + tid];
#pragma unroll
  for (int jj = 0; jj < 8; ++jj) {
    int j = tx8 + jj;
#pragma unroll
    for (int mm = 0; mm < 4; ++mm)
      rT[j * 64 + ((ty4 + mm + j) & 63)] = c1[mm][jj];
  }
  __syncthreads();
  // ---- GEMM2 ----
  float c2[4][4];
#pragma unroll
  for (int mm = 0; mm < 4; ++mm)
#pragma unroll
    for (int ii = 0; ii < 4; ++ii) c2[mm][ii] = 0.f;
  for (int j = 0; j < 128; ++j) {
    float a0 = rT[j * 64 + ((ty4 + 0 + j) & 63)];
    float a1 = rT[j * 64 + ((ty4 + 1 + j) & 63)];
    float a2 = rT[j * 64 + ((ty4 + 2 + j) & 63)];
    float a3 = rT[j * 64 + ((ty4 + 3 + j) & 63)];
    float4 b = *(const float4*)&w2s[j * 64 + tx4];
    float av[4] = {a0, a1, a2, a3};
    float bv[4] = {b.x, b.y, b.z, b.w};
#pragma unroll
    for (int mm = 0; mm < 4; ++mm)
#pragma unroll
      for (int ii = 0; ii < 4; ++ii) c2[mm][ii] += av[mm] * bv[ii];
  }
  // ---- +b2, LN over each node row (reduce across tx via shfl), relu, residual ----
  {
    float4 bb = *(const float4*)&b2[tx4];
    float bv[4] = {bb.x, bb.y, bb.z, bb.w};
#pragma unroll
    for (int mm = 0; mm < 4; ++mm)
#pragma unroll
      for (int ii = 0; ii < 4; ++ii) c2[mm][ii] += bv[ii];
  }
  float s1[4], s2v[4];
#pragma unroll
  for (int mm = 0; mm < 4; ++mm)
    s1[mm] = (c2[mm][0] + c2[mm][1]) + (c2[mm][2] + c2[mm][3]);
#pragma unroll
  for (int msk = 1; msk <= 8; msk <<= 1)
#pragma unroll
    for (int mm = 0; mm < 4; ++mm) s1[mm] += __shfl_xor(s1[mm], msk, 64);
  float mean[4];
#pragma unroll
  for (int mm = 0; mm < 4; ++mm) mean[mm] = s1[mm] * (1.f / 64.f);
#pragma unroll
  for (int mm = 0; mm < 4; ++mm) {
    float d0 = c2[mm][0] - mean[mm], d1 = c2[mm][1] - mean[mm];
    float d2 = c2[mm][2] - mean[mm], d3 = c2[mm][3] - mean[mm];
    s2v[mm] = (d0 * d0 + d1 * d1) + (d2 * d2 + d3 * d3);
  }
#pragma unroll
  for (int msk = 1; msk <= 8; msk <<= 1)
#pragma unroll
    for (int mm = 0; mm < 4; ++mm) s2v[mm] += __shfl_xor(s2v[mm], msk, 64);
  float4 lg = *(const float4*)&lng[tx4];
  float4 lb = *(const float4*)&lnb[tx4];
  float lgv[4] = {lg.x, lg.y, lg.z, lg.w};
  float lbv[4] = {lb.x, lb.y, lb.z, lb.w};
#pragma unroll
  for (int mm = 0; mm < 4; ++mm) {
    int node = nbase + ty4 + mm;
    if (node >= N_NODES) continue;
    float rs = rsqrtf(s2v[mm] * (1.f / 64.f) + 1e-5f);
    float4 res = *(const float4*)&h_in[(size_t)node * HID + tx4];
    float rv[4] = {res.x, res.y, res.z, res.w};
    float outv[4];
#pragma unroll
    for (int ii = 0; ii < 4; ++ii) {
      float v = (c2[mm][ii] - mean[mm]) * rs * lgv[ii] + lbv[ii];
      outv[ii] = fmaxf(v, 0.f) + rv[ii];
    }
    float4 o4; o4.x = outv[0]; o4.y = outv[1]; o4.z = outv[2]; o4.w = outv[3];
    *(float4*)&h_out[(size_t)node * HID + tx4] = o4;
    if (do_pool) {
      int g = batch[node];
#pragma unroll
      for (int ii = 0; ii < 4; ++ii)
        atomicAdd(&add_p[g * HID + tx4 + ii], outv[ii]);
      if (tx == 0) atomicAdd(&cnt[g], 1.f);
    }
  }
}

// GAT precompute: LDS-tiled GEMM (64x64x64), thread tile 4 nodes x 4 outs.
// Head dots reduced over tx-quads via shfl.
__global__ __launch_bounds__(256) void k_gat_pre3(
    const float* __restrict__ h, const float* __restrict__ w,
    const float* __restrict__ asrc, const float* __restrict__ adst,
    float* __restrict__ xp, float* __restrict__ asr, float* __restrict__ adt) {
  __shared__ float smem[64 * ZT_S + 4096];
  float* hT = smem;                   // [64][ZT_S]
  float* ws = smem + 64 * ZT_S;       // [64][64]
  int tid = threadIdx.x;
  int tx = tid & 15, ty = tid >> 4;
  int tx4 = tx * 4, ty4 = ty * 4;
  int nbase = blockIdx.x * 64;
#pragma unroll
  for (int r = 0; r < 4; ++r) {
    int e = r * 256 + tid;
    int nd = e >> 4, kq = e & 15;
    int node = nbase + nd;
    int nc = node < N_NODES ? node : N_NODES - 1;
    float4 v = ((const float4*)(h + (size_t)nc * HID))[kq];
    hT[(kq * 4 + 0) * ZT_S + nd] = v.x;
    hT[(kq * 4 + 1) * ZT_S + nd] = v.y;
    hT[(kq * 4 + 2) * ZT_S + nd] = v.z;
    hT[(kq * 4 + 3) * ZT_S + nd] = v.w;
  }
#pragma unroll
  for (int r = 0; r < 4; ++r)
    ((float4*)ws)[r * 256 + tid] = ((const float4*)w)[r * 256 + tid];
  __syncthreads();
  float c[4][4];
#pragma unroll
  for (int mm = 0; mm < 4; ++mm)
#pragma unroll
    for (int ii = 0; ii < 4; ++ii) c[mm][ii] = 0.f;
  for (int k = 0; k < 64; ++k) {
    float4 a = *(const float4*)&hT[k * ZT_S + ty4];
    float4 b = *(const float4*)&ws[k * 64 + tx4];
    float av[4] = {a.x, a.y, a.z, a.w};
    float bv[4] = {b.x, b.y, b.z, b.w};
#pragma unroll
    for (int mm = 0; mm < 4; ++mm)
#pragma unroll
      for (int ii = 0; ii < 4; ++ii) c[mm][ii] += av[mm] * bv[ii];
  }
  // write xp
#pragma unroll
  for (int mm = 0; mm < 4; ++mm) {
    int node = nbase + ty4 + mm;
    if (node >= N_NODES) continue;
    float4 o4; o4.x = c[mm][0]; o4.y = c[mm][1]; o4.z = c[mm][2]; o4.w = c[mm][3];
    *(float4*)&xp[(size_t)node * HID + tx4] = o4;
  }
  // head dots: head = tx>>2, in-head offset (tx&3)*4
  int hd = tx >> 2, q = tx & 3;
  float4 av4 = *(const float4*)&asrc[hd * 16 + q * 4];
  float4 dv4 = *(const float4*)&adst[hd * 16 + q * 4];
  float pa[4], pd[4];
#pragma unroll
  for (int mm = 0; mm < 4; ++mm) {
    pa[mm] = c[mm][0] * av4.x + c[mm][1] * av4.y + c[mm][2] * av4.z + c[mm][3] * av4.w;
    pd[mm] = c[mm][0] * dv4.x + c[mm][1] * dv4.y + c[mm][2] * dv4.z + c[mm][3] * dv4.w;
  }
#pragma unroll
  for (int msk = 1; msk <= 2; msk <<= 1)
#pragma unroll
    for (int mm = 0; mm < 4; ++mm) {
      pa[mm] += __shfl_xor(pa[mm], msk, 64);
      pd[mm] += __shfl_xor(pd[mm], msk, 64);
    }
  if (q == 0) {
#pragma unroll
    for (int mm = 0; mm < 4; ++mm) {
      int node = nbase + ty4 + mm;
      if (node >= N_NODES) continue;
      asr[node * HEADS + hd] = pa[mm];
      adt[node * HEADS + hd] = pd[mm];
    }
  }
}

// Fused GAT aggregation (wave per node, lane = feature).
__global__ void k_gat_agg(const int* __restrict__ ptr, const int* __restrict__ deg,
                          const int* __restrict__ csr_src,
                          const float* __restrict__ xp, const float* __restrict__ asr,
                          const float* __restrict__ adt,
                          const float* __restrict__ bias,
                          const float* __restrict__ lng, const float* __restrict__ lnb,
                          float* __restrict__ h,
                          int do_pool, const int* __restrict__ batch,
                          float* __restrict__ sum_p, unsigned* __restrict__ max_enc) {
  int n = (blockIdx.x * blockDim.x + threadIdx.x) >> 6;
  int lane = threadIdx.x & 63;
  if (n >= N_NODES) return;
  int head = lane >> 4, sub = lane & 15;
  int base = ptr[n], dg = deg[n];
  float adt_d = adt[n * HEADS + head];
  float el = lrelu02(asr[n * HEADS + head] + adt_d);
  int rem0 = dg < 64 ? dg : 64;
  int idx0 = (lane < rem0) ? csr_src[base + lane] : 0;
  float pm = -1e30f, ps = 0.f;
  for (int c = 0; c < dg; c += 64) {
    int rem = dg - c; if (rem > 64) rem = 64;
    int idx = (c == 0) ? idx0 : ((lane < rem) ? csr_src[base + c + lane] : 0);
    for (int j = sub; j < rem; j += 16) {
      int s = __shfl(idx, j, 64);
      float e = lrelu02(asr[s * HEADS + head] + adt_d);
      float nm = fmaxf(pm, e);
      ps = ps * __expf(pm - nm) + __expf(e - nm);
      pm = nm;
    }
  }
#pragma unroll
  for (int msk = 1; msk <= 8; msk <<= 1) {
    float om = __shfl_xor(pm, msk, 64);
    float os = __shfl_xor(ps, msk, 64);
    float nm = fmaxf(pm, om);
    ps = ps * __expf(pm - nm) + os * __expf(om - nm);
    pm = nm;
  }
  float mfin = fmaxf(pm, el);
  float psum = ps * __expf(pm - mfin) + __expf(el - mfin);
  float o = __expf(el - mfin) * xp[(size_t)n * HID + lane];
  for (int c = 0; c < dg; c += 64) {
    int rem = dg - c; if (rem > 64) rem = 64;
    int idx = (c == 0) ? idx0 : ((lane < rem) ? csr_src[base + c + lane] : 0);
    int it = 0;
    for (; it + 4 <= rem; it += 4) {
      int s0 = __shfl(idx, it, 64);
      int s1 = __shfl(idx, it + 1, 64);
      int s2 = __shfl(idx, it + 2, 64);
      int s3 = __shfl(idx, it + 3, 64);
      float q0 = asr[s0 * HEADS + head];
      float q1 = asr[s1 * HEADS + head];
      float q2 = asr[s2 * HEADS + head];
      float q3 = asr[s3 * HEADS + head];
      float x0 = xp[(size_t)s0 * HID + lane];
      float x1 = xp[(size_t)s1 * HID + lane];
      float x2 = xp[(size_t)s2 * HID + lane];
      float x3 = xp[(size_t)s3 * HID + lane];
      float p0 = __expf(lrelu02(q0 + adt_d) - mfin);
      float p1 = __expf(lrelu02(q1 + adt_d) - mfin);
      float p2 = __expf(lrelu02(q2 + adt_d) - mfin);
      float p3 = __expf(lrelu02(q3 + adt_d) - mfin);
      o += (p0 * x0 + p1 * x1) + (p2 * x2 + p3 * x3);
    }
    for (; it < rem; ++it) {
      int s = __shfl(idx, it, 64);
      float e = lrelu02(asr[s * HEADS + head] + adt_d);
      o += __expf(e - mfin) * xp[(size_t)s * HID + lane];
    }
  }
  o = o / psum + bias[lane];
  float mean = wave_sum64(o) * (1.f / 64.f);
  float d = o - mean;
  float var = wave_sum64(d * d) * (1.f / 64.f);
  float v = d * rsqrtf(var + 1e-5f) * lng[lane] + lnb[lane];
  float e2 = v > 0.f ? v : expm1f(v);
  float hnew = e2 + h[(size_t)n * HID + lane];
  h[(size_t)n * HID + lane] = hnew;
  if (do_pool) {
    int g = batch[n];
    atomicAdd(&sum_p[g * HID + lane], hnew);
    atomicMax(&max_enc[g * HID + lane], enc_f(hnew));
  }
}

// final per-graph MLP. one wave per graph.
__global__ void k_final(const float* __restrict__ add_p, const float* __restrict__ sum_p,
                        const unsigned* __restrict__ max_enc, const float* __restrict__ cnt,
                        const float* __restrict__ fw1, const float* __restrict__ fb1,
                        const float* __restrict__ flng, const float* __restrict__ flnb,
                        const float* __restrict__ fw2, const float* __restrict__ fb2,
                        const float* __restrict__ pw1, const float* __restrict__ pb1,
                        const float* __restrict__ pw2, const float* __restrict__ pb2,
                        float* __restrict__ out) {
  __shared__ float buf[192];
  __shared__ float r1s[64];
  __shared__ float r2s[32];
  __shared__ float r3s[16];
  int g = blockIdx.x;
  int lane = threadIdx.x;
  float c = fmaxf(cnt[g], 1.f);
  buf[lane] = add_p[g * HID + lane];
  buf[64 + lane] = sum_p[g * HID + lane] / c;
  float mx = dec_f(max_enc[g * HID + lane]);
  if (!isfinite(mx)) mx = 0.f;
  buf[128 + lane] = mx;
  __syncthreads();
  float a = fb1[lane];
  for (int k = 0; k < 192; ++k) a += buf[k] * fw1[k * 64 + lane];
  float mean = wave_sum64(a) * (1.f / 64.f);
  float d = a - mean;
  float var = wave_sum64(d * d) * (1.f / 64.f);
  float r = fmaxf(d * rsqrtf(var + 1e-5f) * flng[lane] + flnb[lane], 0.f);
  r1s[lane] = r;
  __syncthreads();
  if (lane < 32) {
    float a2 = fb2[lane];
    for (int k = 0; k < 64; ++k) a2 += r1s[k] * fw2[k * 32 + lane];
    r2s[lane] = fmaxf(a2, 0.f);
  }
  __syncthreads();
  if (lane < 16) {
    float a3 = pb1[lane];
    for (int k = 0; k < 32; ++k) a3 += r2s[k] * pw1[k * 16 + lane];
    r3s[lane] = fmaxf(a3, 0.f);
  }
  __syncthreads();
  if (lane == 0) {
    float a4 = pb2[0];
    for (int k = 0; k < 16; ++k) a4 += r3s[k] * pw2[k];
    out[g] = a4;
  }
}

// ---------- launch ----------

extern "C" void kernel_launch(void* const* d_in, const int* in_sizes, int n_in,
                              void* d_out, int out_size, void* d_ws, size_t ws_size,
                              hipStream_t stream) {
  const float* x = (const float*)d_in[0];
  const float* gf = (const float*)d_in[1];
  const int* ei = (const int*)d_in[2];
  const int* batch = (const int*)d_in[3];
  const float* in_w = (const float*)d_in[4];
  const float* in_b = (const float*)d_in[5];
  const float* in_ln_g = (const float*)d_in[6];
  const float* in_ln_b = (const float*)d_in[7];
  const float* gin_eps = (const float*)d_in[8];
  const float* gin_w1 = (const float*)d_in[9];
  const float* gin_b1 = (const float*)d_in[10];
  const float* gin_bn_g = (const float*)d_in[11];
  const float* gin_bn_b = (const float*)d_in[12];
  const float* gin_bn_m = (const float*)d_in[13];
  const float* gin_bn_v = (const float*)d_in[14];
  const float* gin_w2 = (const float*)d_in[15];
  const float* gin_b2 = (const float*)d_in[16];
  const float* gin_ln_g = (const float*)d_in[17];
  const float* gin_ln_b = (const float*)d_in[18];
  const float* gat_w = (const float*)d_in[19];
  const float* gat_asrc = (const float*)d_in[20];
  const float* gat_adst = (const float*)d_in[21];
  const float* gat_bias = (const float*)d_in[22];
  const float* gat_ln_g = (const float*)d_in[23];
  const float* gat_ln_b = (const float*)d_in[24];
  const float* fus_w1 = (const float*)d_in[25];
  const float* fus_b1 = (const float*)d_in[26];
  const float* fus_ln_g = (const float*)d_in[27];
  const float* fus_ln_b = (const float*)d_in[28];
  const float* fus_w2 = (const float*)d_in[29];
  const float* fus_b2 = (const float*)d_in[30];
  const float* pred_w1 = (const float*)d_in[31];
  const float* pred_b1 = (const float*)d_in[32];
  const float* pred_w2 = (const float*)d_in[33];
  const float* pred_b2 = (const float*)d_in[34];
  float* out = (float*)d_out;

  const int* src = ei;
  const int* dst = ei + N_EDGES;

  char* w = (char*)d_ws;
  float* hA = (float*)w;       w += (size_t)N_NODES * HID * 4;
  float* hB = (float*)w;       w += (size_t)N_NODES * HID * 4;   // GIN ping-pong; GAT xp
  float* zbuf = (float*)w;     w += (size_t)N_NODES * HID * 4;
  float* asr = (float*)w;      w += (size_t)N_NODES * HEADS * 4;
  float* adt = (float*)w;      w += (size_t)N_NODES * HEADS * 4;
  int* deg = (int*)w;          w += (size_t)N_NODES * 4;
  int* ptr = (int*)w;          w += (size_t)N_NODES * 4;
  int* cur = (int*)w;          w += (size_t)N_NODES * 4;
  int* csr_src = (int*)w;      w += (size_t)N_EDGES * 4;
  int* bsum = (int*)w;         w += 512 * 4;
  int* boff = (int*)w;         w += 512 * 4;
  float* add_p = (float*)w;    w += (size_t)N_GRAPHS * HID * 4;
  float* sum_p = (float*)w;    w += (size_t)N_GRAPHS * HID * 4;
  unsigned* max_enc = (unsigned*)w; w += (size_t)N_GRAPHS * HID * 4;
  float* cnt = (float*)w;      w += (size_t)N_GRAPHS * 4;

  dim3 blk(256);
  int nwb = (N_NODES + 3) / 4;            // node-wave blocks (4 waves/block)
  int eb = (N_EDGES + 255) / 256;
  int nb256 = (N_NODES + 255) / 256;

  // --- CSR build ---
  k_zero_int<<<nb256, blk, 0, stream>>>(deg, N_NODES);
  k_hist<<<eb, blk, 0, stream>>>(dst, deg);
  k_blocksum<<<NB_SCAN, blk, 0, stream>>>(deg, bsum);
  k_scanb<<<1, 512, 0, stream>>>(bsum, boff);
  k_offsets<<<NB_SCAN, blk, 0, stream>>>(deg, boff, ptr, cur);
  k_scatter<<<eb, blk, 0, stream>>>(src, dst, cur, csr_src);

  k_pool_init<<<(N_GRAPHS * HID + 255) / 256, blk, 0, stream>>>(add_p, sum_p, max_enc, cnt);
  k_input<<<nwb, blk, 0, stream>>>(x, gf, batch, in_w, in_b, in_ln_g, in_ln_b, hA);

  // --- GIN stack (ping-pong hA -> hB -> hA) ---
  for (int i = 0; i < 2; ++i) {
    const float* hin = (i == 0) ? hA : hB;
    float* hout = (i == 0) ? hB : hA;
    k_gin_gather<<<nwb, blk, 0, stream>>>(ptr, deg, csr_src, hin, zbuf, gin_eps + i);
    k_gin_mlp2<<<NBLK, blk, 0, stream>>>(zbuf, hin, hout,
        gin_w1 + (size_t)i * 64 * 128, gin_b1 + i * 128,
        gin_bn_g + i * 128, gin_bn_b + i * 128, gin_bn_m + i * 128, gin_bn_v + i * 128,
        gin_w2 + (size_t)i * 128 * 64, gin_b2 + i * 64,
        gin_ln_g + i * 64, gin_ln_b + i * 64,
        (i == 1) ? 1 : 0, batch, add_p, cnt);
  }

  // --- GAT stack (in place on hA; hB reused as xp) ---
  for (int i = 0; i < 2; ++i) {
    k_gat_pre3<<<NBLK, blk, 0, stream>>>(hA, gat_w + (size_t)i * 64 * 64,
        gat_asrc + i * HEADS * HEAD_DIM, gat_adst + i * HEADS * HEAD_DIM,
        hB, asr, adt);
    k_gat_agg<<<nwb, blk, 0, stream>>>(ptr, deg, csr_src, hB, asr, adt,
        gat_bias + i * 64, gat_ln_g + i * 64, gat_ln_b + i * 64, hA,
        (i == 1) ? 1 : 0, batch, sum_p, max_enc);
  }

  k_final<<<N_GRAPHS, 64, 0, stream>>>(add_p, sum_p, max_enc, cnt,
      fus_w1, fus_b1, fus_ln_g, fus_ln_b, fus_w2, fus_b2,
      pred_w1, pred_b1, pred_w2, pred_b2, out);
}